// Round 14
// baseline (413.855 us; speedup 1.0000x reference)
//
#include <hip/hip_runtime.h>
#include <hip/hip_cooperative_groups.h>
#include <cstdint>
#include <cstddef>
#include <cmath>

#pragma clang fp contract(off)

namespace cg = cooperative_groups;

namespace {

constexpr int kCandMax = 4096;

__device__ __constant__ int c_N[5] = {196608, 49152, 12288, 3072, 768};
__device__ __constant__ int c_K[5] = {1000, 1000, 1000, 1000, 768};

struct RPNParams {
  const float* deltas[5];
  const float* ctr[5];
  const float* anchors[5];
  float* scores;         // [8][5][1024] masked scores, per-level sorted desc
  float* boxes;          // [8][5][1024][4] clipped boxes, per-level sorted
  unsigned char* keep;   // [8][5][1024]
  unsigned int* mask;    // [8][5][1024][32]; own-pair u64 holds TRANSPOSED bits
  unsigned int* g0p;     // [40][32][256] partial hist level 0 (aliases mask region)
  unsigned int* g1p;     // [40][32][256] partial hist level 1 (aliases mask region)
  unsigned int* ccount;  // [40] at stride 256 u32 (own cache line each)
  unsigned int* v0kk;    // [40][2]: (v0, kk)
  unsigned long long* cand;  // [40][4096] (aliases mask region; used before k_mask)
  unsigned long long* keyC;  // [40][1024] valid-partitioned composite keys
  float* out;            // [8][1000][5]
};

// monotonic float->uint map (larger float => larger uint)
__device__ __forceinline__ unsigned int fkey(float f) {
  unsigned int u = __float_as_uint(f);
  return (u & 0x80000000u) ? ~u : (u | 0x80000000u);
}

__device__ __forceinline__ unsigned long long readlane64(unsigned long long v, int lane) {
  unsigned int lo = __builtin_amdgcn_readlane((unsigned int)v, lane);
  unsigned int hi = __builtin_amdgcn_readlane((unsigned int)(v >> 32), lane);
  return ((unsigned long long)hi << 32) | (unsigned long long)lo;
}

// shared-memory layout for the fused phase-1 (hist0 / hist1 / compact)
struct Phase1Smem {
  unsigned int wh16[4][4][257];  // 16 sub-hists, 257-padding spreads banks
  unsigned int wh1[4][256];
  unsigned int S[257];
  unsigned int wcnt[4], wbase[4];
};

// ---------------- Phase A: 8-bit partial histograms (plain stores) -------
__device__ __forceinline__ void phaseA_hist0(const RPNParams& P, Phase1Smem& sm,
                                             int bl, int y) {
  int b = bl / 5, l = bl % 5;
  int N = c_N[l];
  int chunk = (N + 31) / 32;  // multiples of 4
  int i0 = y * chunk;
  int i1 = i0 + chunk; if (i1 > N) i1 = N;
  const float4* c4 = (const float4*)(P.ctr[l] + (size_t)b * N);
  int tid = threadIdx.x, wid = tid >> 6, sg = tid & 3;
  if (y == 0 && tid == 0) P.ccount[bl * 256] = 0u;  // pre-zero for compact phase
  for (int i = tid; i < 4 * 4 * 257; i += 256) ((unsigned int*)sm.wh16)[i] = 0u;
  __syncthreads();
  unsigned int* myh = sm.wh16[wid][sg];
  int q0 = i0 >> 2, q1 = i1 >> 2;
  for (int q = q0 + tid; q < q1; q += 256) {
    float4 v = c4[q];
    atomicAdd(&myh[fkey(v.x) >> 24], 1u);
    atomicAdd(&myh[fkey(v.y) >> 24], 1u);
    atomicAdd(&myh[fkey(v.z) >> 24], 1u);
    atomicAdd(&myh[fkey(v.w) >> 24], 1u);
  }
  __syncthreads();
  int bin = tid;
  unsigned int s = 0;
  #pragma unroll
  for (int w = 0; w < 4; ++w)
    #pragma unroll
    for (int k2 = 0; k2 < 4; ++k2) s += sm.wh16[w][k2][bin];
  P.g0p[((size_t)bl * 32 + y) * 256 + bin] = s;
}

// -------- Phase B: 16-bit partial refine (v0 computed per block) ---------
__device__ __forceinline__ void phaseB_hist1(const RPNParams& P, Phase1Smem& sm,
                                             int bl, int y) {
  int b = bl / 5, l = bl % 5;
  int N = c_N[l], K = c_K[l];
  int chunk = (N + 31) / 32;
  int i0 = y * chunk;
  int i1 = i0 + chunk; if (i1 > N) i1 = N;
  const float4* c4 = (const float4*)(P.ctr[l] + (size_t)b * N);
  int tid = threadIdx.x, wid = tid >> 6;
  // per-block v0 from g0p partials (L2-hot; hidden by occupancy)
  {
    unsigned int s = 0;
    const unsigned int* base0 = P.g0p + (size_t)bl * 32 * 256 + tid;
    #pragma unroll 8
    for (int p = 0; p < 32; ++p) s += base0[p * 256];
    sm.S[tid] = s;
    if (tid == 0) sm.S[256] = 0u;
  }
  __syncthreads();
  for (int d = 1; d < 256; d <<= 1) {
    unsigned int v = (tid + d < 256) ? sm.S[tid + d] : 0u;
    __syncthreads();
    sm.S[tid] += v;
    __syncthreads();
  }
  int lo = 0, hi = 255;
  while (lo < hi) { int mid = (lo + hi + 1) >> 1; if (sm.S[mid] >= (unsigned int)K) lo = mid; else hi = mid - 1; }
  unsigned int v0 = (unsigned int)lo;
  if (y == 0 && tid == 0) {
    P.v0kk[bl * 2] = v0;
    P.v0kk[bl * 2 + 1] = (unsigned int)K - sm.S[lo + 1];
  }
  for (int i = tid; i < 1024; i += 256) ((unsigned int*)sm.wh1)[i] = 0u;
  __syncthreads();
  int q0 = i0 >> 2, q1 = i1 >> 2;
  for (int q = q0 + tid; q < q1; q += 256) {
    float4 v = c4[q];
    unsigned int u0 = fkey(v.x), u1 = fkey(v.y), u2 = fkey(v.z), u3 = fkey(v.w);
    if ((u0 >> 24) == v0) atomicAdd(&sm.wh1[wid][(u0 >> 16) & 255u], 1u);
    if ((u1 >> 24) == v0) atomicAdd(&sm.wh1[wid][(u1 >> 16) & 255u], 1u);
    if ((u2 >> 24) == v0) atomicAdd(&sm.wh1[wid][(u2 >> 16) & 255u], 1u);
    if ((u3 >> 24) == v0) atomicAdd(&sm.wh1[wid][(u3 >> 16) & 255u], 1u);
  }
  __syncthreads();
  int bin = tid;
  P.g1p[((size_t)bl * 32 + y) * 256 + bin] =
      sm.wh1[0][bin] + sm.wh1[1][bin] + sm.wh1[2][bin] + sm.wh1[3][bin];
}

// ---- Phase C: compaction; T computed per block; one atomic per block ----
__device__ __forceinline__ void phaseC_compact(const RPNParams& P, Phase1Smem& sm,
                                               int bl, int y) {
  int b = bl / 5, l = bl % 5;
  int N = c_N[l];
  int chunk = (N + 31) / 32;
  int i0 = y * chunk;
  int i1 = i0 + chunk; if (i1 > N) i1 = N;
  const float4* c4 = (const float4*)(P.ctr[l] + (size_t)b * N);
  unsigned long long* cand = P.cand + (size_t)bl * kCandMax;
  int tid = threadIdx.x, lane = tid & 63, wid = tid >> 6;
  __syncthreads();  // protect sm.S reuse across phases
  {
    unsigned int s = 0;
    const unsigned int* base1 = P.g1p + (size_t)bl * 32 * 256 + tid;
    #pragma unroll 8
    for (int p = 0; p < 32; ++p) s += base1[p * 256];
    sm.S[tid] = s;
    if (tid == 0) sm.S[256] = 0u;
  }
  __syncthreads();
  for (int d = 1; d < 256; d <<= 1) {
    unsigned int v = (tid + d < 256) ? sm.S[tid + d] : 0u;
    __syncthreads();
    sm.S[tid] += v;
    __syncthreads();
  }
  unsigned int v0 = P.v0kk[bl * 2], kk = P.v0kk[bl * 2 + 1];
  int lo = 0, hi = 255;
  while (lo < hi) { int mid = (lo + hi + 1) >> 1; if (sm.S[mid] >= kk) lo = mid; else hi = mid - 1; }
  unsigned int T = ((v0 << 8) | (unsigned int)lo) << 16;
  int q0 = i0 >> 2, q1 = i1 >> 2;
  // pass 1: count
  unsigned int cnt = 0;
  for (int q = q0 + tid; q < q1; q += 256) {
    float4 v = c4[q];
    cnt += (fkey(v.x) >= T) + (fkey(v.y) >= T) + (fkey(v.z) >= T) + (fkey(v.w) >= T);
  }
  for (int d = 32; d > 0; d >>= 1) cnt += (unsigned int)__shfl_xor((int)cnt, d, 64);
  if (lane == 0) sm.wcnt[wid] = cnt;
  __syncthreads();
  if (tid == 0) {
    unsigned int tot = sm.wcnt[0] + sm.wcnt[1] + sm.wcnt[2] + sm.wcnt[3];
    unsigned int base = tot ? atomicAdd(&P.ccount[bl * 256], tot) : 0u;
    unsigned int acc = base;
    for (int w = 0; w < 4; ++w) { unsigned int x = sm.wcnt[w]; sm.wbase[w] = acc; acc += x; }
  }
  __syncthreads();
  unsigned int off = sm.wbase[wid];
  unsigned long long lmlt = (1ull << lane) - 1ull;
  for (int q = q0 + tid; q < q1; q += 256) {
    float4 v = c4[q];
    unsigned int u[4] = {fkey(v.x), fkey(v.y), fkey(v.z), fkey(v.w)};
    #pragma unroll
    for (int k = 0; k < 4; ++k) {
      bool pred = (u[k] >= T);
      unsigned long long m = __ballot(pred);
      if (pred) {
        unsigned int pos = off + (unsigned int)__popcll(m & lmlt);
        if (pos < (unsigned int)kCandMax) {
          unsigned int idx = (unsigned int)(q * 4 + k);
          cand[pos] = ((unsigned long long)u[k] << 32) |
                      (unsigned long long)(0xFFFFFFFFu - idx);
        }
      }
      off += (unsigned int)__popcll(m);
    }
  }
}

// -------- fused cooperative phase-1 kernel (2 grid syncs) ----------------
__global__ __launch_bounds__(256) void k_phase1(RPNParams P) {
  __shared__ Phase1Smem sm;
  cg::grid_group grid = cg::this_grid();
  int bl = blockIdx.x, y = blockIdx.y;
  phaseA_hist0(P, sm, bl, y);
  grid.sync();
  phaseB_hist1(P, sm, bl, y);
  grid.sync();
  phaseC_compact(P, sm, bl, y);
}

// -------- fallback standalone kernels (identical phase bodies) -----------
__global__ __launch_bounds__(256) void k_hist0(RPNParams P) {
  __shared__ Phase1Smem sm;
  phaseA_hist0(P, sm, blockIdx.x, blockIdx.y);
}
__global__ __launch_bounds__(256) void k_hist1(RPNParams P) {
  __shared__ Phase1Smem sm;
  phaseB_hist1(P, sm, blockIdx.x, blockIdx.y);
}
__global__ __launch_bounds__(256) void k_compact(RPNParams P) {
  __shared__ Phase1Smem sm;
  phaseC_compact(P, sm, blockIdx.x, blockIdx.y);
}

// -- Phase 1d: sort, decode+clip, write valid-partitioned keyC (40 blocks) --
__global__ __launch_bounds__(1024) void k_select(RPNParams P) {
  int bl = blockIdx.x, b = bl / 5, l = bl % 5;
  int N = c_N[l], K = c_K[l];
  const float* ctr = P.ctr[l] + (size_t)b * N;
  __shared__ unsigned long long cand[kCandMax];
  __shared__ unsigned int wsum[16];
  __shared__ unsigned int sTot;
  int tid = threadIdx.x;
  int lane = tid & 63, wid = tid >> 6;
  int cc = (int)P.ccount[bl * 256]; if (cc > kCandMax) cc = kCandMax;
  const unsigned long long* gc = P.cand + (size_t)bl * kCandMax;
  for (int i = tid; i < cc; i += 1024) cand[i] = gc[i];
  int n2 = 1; while (n2 < cc) n2 <<= 1;
  for (int i = cc + tid; i < n2; i += 1024) cand[i] = 0ull;
  __syncthreads();
  // bitonic sort descending by (key desc, idx asc) composite
  for (int size = 2; size <= n2; size <<= 1) {
    for (int stride = size >> 1; stride > 0; stride >>= 1) {
      for (int i = tid; i < n2; i += 1024) {
        int j = i ^ stride;
        if (j > i) {
          unsigned long long a = cand[i], c2 = cand[j];
          bool sw = ((i & size) == 0) ? (a < c2) : (a > c2);
          if (sw) { cand[i] = c2; cand[j] = a; }
        }
      }
      __syncthreads();
    }
  }
  size_t sbase = ((size_t)b * 5 + l) * 1024;
  int r = tid;  // K <= 1000 < 1024: single round
  unsigned long long kc = 0ull;
  bool flag = false;
  if (r < K) {
    unsigned long long cv = cand[r];
    unsigned int idx = 0xFFFFFFFFu - (unsigned int)(cv & 0xFFFFFFFFu);
    float s = ctr[idx];
    float4 anc = *(const float4*)(P.anchors[l] + (size_t)idx * 4);
    float4 dd  = *(const float4*)(P.deltas[l] + ((size_t)b * N + idx) * 4);
    // Box2BoxTransformLinear decode (same op order as reference, no fma)
    float w = anc.z - anc.x, hgt = anc.w - anc.y;
    float cx = (anc.x + anc.z) * 0.5f, cy = (anc.y + anc.w) * 0.5f;
    float x1 = cx - dd.x * w;
    float y1 = cy - dd.y * hgt;
    float x2 = cx + dd.z * w;
    float y2 = cy + dd.w * hgt;
    x1 = fminf(fmaxf(x1, 0.0f), 1024.0f);
    y1 = fminf(fmaxf(y1, 0.0f), 1024.0f);
    x2 = fminf(fmaxf(x2, 0.0f), 1024.0f);
    y2 = fminf(fmaxf(y2, 0.0f), 1024.0f);
    bool valid = ((x2 - x1) > 0.0f) && ((y2 - y1) > 0.0f);
    float sc = valid ? s : -INFINITY;
    P.scores[sbase + r] = sc;
    *(float4*)(P.boxes + (sbase + r) * 4) = make_float4(x1, y1, x2, y2);
    unsigned int fk = fkey(sc);
    flag = fk > 0x007FFFFFu;  // score > -inf
    unsigned int cidx = (unsigned int)(l * 1000 + r);
    kc = ((unsigned long long)fk << 32) |
         (unsigned long long)(0xFFFFFFFFu - cidx);
  }
  // stable partition (valid first) -> keyC, strictly descending composite
  unsigned int fv = flag ? 1u : 0u, v = fv;
  for (int d = 1; d < 64; d <<= 1) {
    unsigned int n = __shfl_up(v, (unsigned int)d, 64);
    if (lane >= d) v += n;
  }
  if (lane == 63) wsum[wid] = v;
  __syncthreads();
  if (tid == 0) {
    unsigned int acc = 0;
    for (int w = 0; w < 16; ++w) { unsigned int x = wsum[w]; wsum[w] = acc; acc += x; }
    sTot = acc;
  }
  __syncthreads();
  unsigned int excl = wsum[wid] + (v - fv);
  if (r < K) {
    unsigned int dest = flag ? excl : (sTot + ((unsigned int)r - excl));
    P.keyC[(size_t)bl * 1024 + dest] = kc;
  }
}

// ---------------- Phase 2a: suppression bitmask (per level) ---------------
__global__ __launch_bounds__(512) void k_mask(RPNParams P) {
  int bl = blockIdx.x, b = bl / 5, l = bl % 5;
  int K = c_K[l];
  int tid = threadIdx.x;
  int lane = tid & 63;
  int yg = blockIdx.y * 8 + (tid >> 6);   // row-group 0..15
  int zc = blockIdx.z;                    // column sixteenth 0..15
  float off = (float)l * 1025.0f;  // lvl * (IMG + 1) — replicate offset rounding!
  size_t sbase = ((size_t)b * 5 + l) * 1024;
  __shared__ alignas(16) float4 obox[1024];
  __shared__ float area[1024];
  for (int i = tid; i < 1024; i += 512) {
    float4 v = make_float4(0.f, 0.f, 0.f, 0.f);
    if (i < K) {
      v = ((const float4*)P.boxes)[sbase + i];
      v.x += off; v.y += off; v.z += off; v.w += off;
    }
    obox[i] = v;
    area[i] = fmaxf(v.z - v.x, 0.0f) * fmaxf(v.w - v.y, 0.0f);
  }
  __syncthreads();
  int i = yg * 64 + lane;
  if (i >= K) return;  // after the barrier; no further barriers below
  float4 bi = obox[i];
  float ai = area[i];
  unsigned int* mrow = P.mask + (sbase + (size_t)i) * 32;
  const double M = 0x1.666667p-1;  // 0.7f + 2^-25
  auto pr = [&](int j) -> bool {
    float4 bj = obox[j];
    float aj = area[j];
    float xx1 = fmaxf(bi.x, bj.x);
    float yy1 = fmaxf(bi.y, bj.y);
    float xx2 = fminf(bi.z, bj.z);
    float yy2 = fminf(bi.w, bj.w);
    float ww = fmaxf(xx2 - xx1, 0.0f);
    float hh = fmaxf(yy2 - yy1, 0.0f);
    float inter = ww * hh;
    float uni = ai + aj - inter + 1e-8f;  // ((ai+aj)-inter)+eps, f32 order
    return (double)inter >= M * (double)uni;
  };
  int wown = 2 * yg;
  if (zc == 0) {
    for (int w = 0; w < wown; ++w) mrow[w] = 0u;  // low words: all j < own pair
    // own word pair: transposed (j < i) bits
    unsigned int m0, m1;
    if (lane < 32) { m0 = (1u << lane) - 1u; m1 = 0u; }
    else           { m0 = 0xFFFFFFFFu; m1 = (1u << (lane - 32)) - 1u; }
    #pragma unroll
    for (int h = 0; h < 2; ++h) {
      unsigned int bits = 0u;
      int j0 = (wown + h) << 5;
      for (int jj = 0; jj < 32; ++jj)
        if (pr(j0 + jj)) bits |= (1u << jj);
      mrow[wown + h] = bits & (h ? m1 : m0);
    }
  }
  int wstart = wown + 2;
  int nw = 32 - wstart;
  int qlen = (nw + 15) >> 4;
  int wbeg = wstart + zc * qlen;
  int wend = wbeg + qlen; if (wend > 32) wend = 32;
  for (int w = wbeg; w < wend; ++w) {
    unsigned int bits = 0u;
    int j0 = w << 5;
    for (int jj = 0; jj < 32; ++jj)
      if (pr(j0 + jj)) bits |= (1u << jj);  // j > i guaranteed (w > own pair)
    mrow[w] = bits;
  }
}

// ---------------- Phase 2b: greedy sweep, parallel peel -------------------
__global__ __launch_bounds__(1024) void k_sweep(RPNParams P) {
  int bl = blockIdx.x, b = bl / 5, l = bl % 5;
  int K = c_K[l];
  int NW = (K + 63) >> 6;
  size_t sbase = ((size_t)b * 5 + l) * 1024;
  __shared__ alignas(16) unsigned long long lmask[16 * 1000];  // 125 KiB [row][16]
  __shared__ unsigned long long rdiag[1024];  // colmask per row (earlier in-word)
  __shared__ unsigned long long svalid[16];
  __shared__ unsigned long long skept[16];
  int tid = threadIdx.x;
  const ulonglong2* gm2 = (const ulonglong2*)(P.mask + sbase * 32);
  for (int j = tid; j < K * 8; j += 1024) {
    ulonglong2 v = gm2[j];
    ((ulonglong2*)lmask)[j] = v;
    int w0i = j * 2;       // u64 index within the matrix
    int row = w0i >> 4;
    int dcol = row >> 6;   // the row's own-word u64 slot
    int col0 = w0i & 15;
    if (col0 == dcol) rdiag[row] = v.x;
    else if (col0 + 1 == dcol) rdiag[row] = v.y;
  }
  // valid ballots computed by all 16 waves in parallel (wave g -> word g)
  {
    int g = tid >> 6;
    int e = g * 64 + (tid & 63);
    bool pred = (e < K) && (P.scores[sbase + e] > -INFINITY);
    unsigned long long m = __ballot(pred);
    if ((tid & 63) == 0) svalid[g] = m;
  }
  __syncthreads();
  if (tid >= 64) return;  // single wave from here; no further barriers
  int lane = tid;
  int sub = lane >> 4, col = lane & 15;
  unsigned long long accA = 0ull, accB = 0ull;  // per-lane partial OR of kept rows
  for (int g = 0; g < NW; ++g) {
    // combine the 4 subset-partials for column g (lanes g, g+16, g+32, g+48)
    unsigned long long am = accA | accB;
    unsigned long long suppr = readlane64(am, g) | readlane64(am, g + 16) |
                               readlane64(am, g + 32) | readlane64(am, g + 48);
    unsigned long long A = svalid[g] & ~suppr;   // alive set (wave-uniform value)
    unsigned long long colmask = rdiag[g * 64 + lane];  // earlier in-word suppressors
    unsigned long long kept = 0ull;
    while (A) {  // level-synchronous peel == sequential greedy
      bool cand = (A >> lane) & 1ull;
      unsigned long long D = __ballot(cand && ((colmask & A) == 0ull));
      kept |= D;
      unsigned long long sup = __ballot((colmask & D) != 0ull);
      A &= ~(D | sup);
    }
    if (lane == 0) skept[g] = kept;
    // static unrolled OR of kept rows into per-lane acc (columns for later words)
    const unsigned long long* rowbase = &lmask[((size_t)g * 64 + (size_t)sub) * 16 + col];
    #pragma unroll
    for (int t = 0; t < 8; ++t) {
      int p0 = (2 * t) * 4 + sub;
      int p1 = (2 * t + 1) * 4 + sub;
      unsigned long long s0 = 0ull - ((kept >> p0) & 1ull);
      unsigned long long s1 = 0ull - ((kept >> p1) & 1ull);
      accA |= rowbase[(size_t)(2 * t) * 64] & s0;
      accB |= rowbase[(size_t)(2 * t + 1) * 64] & s1;
    }
  }
  for (int g = 0; g < NW; ++g) {
    unsigned long long kv = skept[g];
    int e = g * 64 + lane;
    if (e < K) P.keep[sbase + e] = (unsigned char)((kv >> lane) & 1ull);
  }
}

// ------- Phase 3: per-image 5-way merge-by-rank + keep-partition + out ----
__global__ __launch_bounds__(1024) void k_merge(RPNParams P) {
  int b = blockIdx.x;
  __shared__ unsigned long long keyL[5][1000];  // 40 KB, strictly desc per level
  __shared__ unsigned short srt[4768];          // rank -> concat idx
  __shared__ unsigned int wsum[16];
  __shared__ unsigned int sTot;
  int tid = threadIdx.x;
  int lane = tid & 63, wid = tid >> 6;

  // ---- Step 1: load pre-partitioned keys (from k_select) ----
  #pragma unroll
  for (int l = 0; l < 5; ++l)
    if (tid < c_K[l]) keyL[l][tid] = P.keyC[((size_t)b * 5 + l) * 1024 + tid];
  __syncthreads();

  // ---- Step 2: global rank via binary search in the other 4 lists ----
  for (int e = tid; e < 4768; e += 1024) {
    int l = (e < 4000) ? (e / 1000) : 4;
    int p = e - l * 1000;
    unsigned long long k = keyL[l][p];
    int rank = p;
    #pragma unroll
    for (int l2 = 0; l2 < 5; ++l2) {
      if (l2 == l) continue;
      int lo = 0, hi = c_K[l2];
      while (lo < hi) {
        int mid = (lo + hi) >> 1;
        if (keyL[l2][mid] > k) lo = mid + 1; else hi = mid;
      }
      rank += lo;
    }
    srt[rank] = (unsigned short)(0xFFFFFFFFu - (unsigned int)(k & 0xFFFFFFFFu));
  }
  __syncthreads();

  // ---- Step 3: keep flags for 5 contiguous sorted slots per thread ----
  int base = tid * 5;
  unsigned char lf[5];
  unsigned short lc[5];
  unsigned int lsum = 0;
  for (int q = 0; q < 5; ++q) {
    int i = base + q;
    unsigned char f = 0; unsigned short cx = 0;
    if (i < 4768) {
      cx = srt[i];
      int l = cx / 1000;
      int r = (int)cx - l * 1000;
      f = P.keep[((size_t)b * 5 + l) * 1024 + r];
    }
    lf[q] = f; lc[q] = cx; lsum += f;
  }
  unsigned int v = lsum;
  for (int d = 1; d < 64; d <<= 1) {
    unsigned int n = __shfl_up(v, (unsigned int)d, 64);
    if (lane >= d) v += n;
  }
  if (lane == 63) wsum[wid] = v;
  __syncthreads();
  if (tid == 0) {
    unsigned int acc = 0;
    for (int w = 0; w < 16; ++w) { unsigned int x = wsum[w]; wsum[w] = acc; acc += x; }
    sTot = acc;
  }
  __syncthreads();
  unsigned int excl = wsum[wid] + (v - lsum);  // kept count before slot `base`
  unsigned int tot = sTot;
  for (int q = 0; q < 5; ++q) {
    int i = base + q;
    if (i >= 4768) break;
    unsigned int cidx = (unsigned int)lc[q];
    int l = (int)(cidx / 1000u);
    int r = (int)cidx - l * 1000;
    size_t sb = ((size_t)b * 5 + l) * 1024 + r;
    unsigned char f = lf[q];
    unsigned int pos = f ? excl : (tot + ((unsigned int)i - excl));
    excl += f;
    if (pos < 1000u) {
      float4 bx = ((const float4*)P.boxes)[sb];
      float sc = f ? P.scores[sb] : -INFINITY;
      float* o = P.out + ((size_t)b * 1000 + pos) * 5;
      o[0] = bx.x; o[1] = bx.y; o[2] = bx.z; o[3] = bx.w; o[4] = sc;
    }
  }
}

}  // namespace

extern "C" void kernel_launch(void* const* d_in, const int* in_sizes, int n_in,
                              void* d_out, int out_size, void* d_ws, size_t ws_size,
                              hipStream_t stream) {
  (void)out_size; (void)ws_size;
  RPNParams P;
  bool interleaved = (n_in >= 3) && (in_sizes[2] == 786432);
  for (int l = 0; l < 5; ++l) {
    if (interleaved) {
      P.deltas[l]  = (const float*)d_in[3 * l + 0];
      P.ctr[l]     = (const float*)d_in[3 * l + 1];
      P.anchors[l] = (const float*)d_in[3 * l + 2];
    } else {
      P.deltas[l]  = (const float*)d_in[l];
      P.ctr[l]     = (const float*)d_in[5 + l];
      P.anchors[l] = (const float*)d_in[10 + l];
    }
  }
  char* ws = (char*)d_ws;
  P.scores = (float*)(ws + 0);                    // 163840 B
  P.boxes  = (float*)(ws + 163840);               // 655360 B
  P.keep   = (unsigned char*)(ws + 819200);       // 40960 B
  P.mask   = (unsigned int*)(ws + 860160);        // 5242880 B
  // aliases inside the mask region (all used strictly before k_mask writes):
  P.cand   = (unsigned long long*)(ws + 860160);  // 1310720 B
  P.g0p    = (unsigned int*)(ws + 2170880);       // 1310720 B
  P.g1p    = (unsigned int*)(ws + 3481600);       // 1310720 B
  // small control arrays (all rewritten every launch; no init needed):
  P.ccount = (unsigned int*)(ws + 6103040);       // 40 entries at stride 256 u32
  P.v0kk   = (unsigned int*)(ws + 6144000);       // 320 B
  P.keyC   = (unsigned long long*)(ws + 6144320); // 327680 B
  P.out    = (float*)d_out;

  // fused phase-1 (hist0 + hist1 + compact) via cooperative launch;
  // deterministic fallback to the three standalone kernels if rejected.
  void* kargs[] = { (void*)&P };
  hipError_t ce = hipLaunchCooperativeKernel((const void*)k_phase1,
                                             dim3(40, 32), dim3(256),
                                             kargs, 0, stream);
  if (ce != hipSuccess) {
    hipLaunchKernelGGL(k_hist0, dim3(40, 32), dim3(256), 0, stream, P);
    hipLaunchKernelGGL(k_hist1, dim3(40, 32), dim3(256), 0, stream, P);
    hipLaunchKernelGGL(k_compact, dim3(40, 32), dim3(256), 0, stream, P);
  }
  hipLaunchKernelGGL(k_select, dim3(40), dim3(1024), 0, stream, P);
  hipLaunchKernelGGL(k_mask, dim3(40, 2, 16), dim3(512), 0, stream, P);
  hipLaunchKernelGGL(k_sweep, dim3(40), dim3(1024), 0, stream, P);
  hipLaunchKernelGGL(k_merge, dim3(8), dim3(1024), 0, stream, P);
}

// Round 15
// 128.484 us; speedup vs baseline: 3.2211x; 3.2211x over previous
//
#include <hip/hip_runtime.h>
#include <cstdint>
#include <cstddef>
#include <cmath>

#pragma clang fp contract(off)

namespace {

constexpr int kCandMax = 4096;

__device__ __constant__ int c_N[5] = {196608, 49152, 12288, 3072, 768};
__device__ __constant__ int c_K[5] = {1000, 1000, 1000, 1000, 768};

struct RPNParams {
  const float* deltas[5];
  const float* ctr[5];
  const float* anchors[5];
  float* scores;         // [8][5][1024] masked scores, per-level sorted desc
  float* boxes;          // [8][5][1024][4] clipped boxes, per-level sorted
  unsigned char* keep;   // [8][5][1024]
  unsigned int* mask;    // [8][5][1024][32]; own-pair u64 holds TRANSPOSED bits
  unsigned int* g0p;     // [40][32][256] partial hist level 0 (aliases mask region)
  unsigned int* g1p;     // [40][32][256] partial hist level 1 (aliases mask region)
  unsigned int* v0kk;    // [40][2]: (v0, kk)
  unsigned long long* keyC;  // [40][1024] valid-partitioned composite keys
  float* out;            // [8][1000][5]
};

// monotonic float->uint map (larger float => larger uint)
__device__ __forceinline__ unsigned int fkey(float f) {
  unsigned int u = __float_as_uint(f);
  return (u & 0x80000000u) ? ~u : (u | 0x80000000u);
}

__device__ __forceinline__ unsigned long long readlane64(unsigned long long v, int lane) {
  unsigned int lo = __builtin_amdgcn_readlane((unsigned int)v, lane);
  unsigned int hi = __builtin_amdgcn_readlane((unsigned int)(v >> 32), lane);
  return ((unsigned long long)hi << 32) | (unsigned long long)lo;
}

// ---------------- Phase 1a: 8-bit partial histograms (plain stores) ------
// 16 sub-histograms (wave x lane&3, 257-padded) cut same-address LDS-atomic
// serialization ~4x on the hot normal-distribution exponent bins.
__global__ __launch_bounds__(256) void k_hist0(RPNParams P) {
  int bl = blockIdx.x, b = bl / 5, l = bl % 5;
  int N = c_N[l];
  int chunk = (N + 31) / 32;  // multiples of 4
  int i0 = blockIdx.y * chunk;
  int i1 = i0 + chunk; if (i1 > N) i1 = N;
  const float4* c4 = (const float4*)(P.ctr[l] + (size_t)b * N);
  __shared__ unsigned int wh16[4][4][257];
  int tid = threadIdx.x, wid = tid >> 6, sg = tid & 3;
  for (int i = tid; i < 4 * 4 * 257; i += 256) ((unsigned int*)wh16)[i] = 0u;
  __syncthreads();
  unsigned int* myh = wh16[wid][sg];
  int q0 = i0 >> 2, q1 = i1 >> 2;
  for (int q = q0 + tid; q < q1; q += 256) {
    float4 v = c4[q];
    atomicAdd(&myh[fkey(v.x) >> 24], 1u);
    atomicAdd(&myh[fkey(v.y) >> 24], 1u);
    atomicAdd(&myh[fkey(v.z) >> 24], 1u);
    atomicAdd(&myh[fkey(v.w) >> 24], 1u);
  }
  __syncthreads();
  int bin = tid;
  unsigned int s = 0;
  #pragma unroll
  for (int w = 0; w < 4; ++w)
    #pragma unroll
    for (int k2 = 0; k2 < 4; ++k2) s += wh16[w][k2][bin];
  P.g0p[((size_t)bl * 32 + blockIdx.y) * 256 + bin] = s;
}

// -------- Phase 1b: 16-bit partial refine (v0 computed per block) --------
__global__ __launch_bounds__(256) void k_hist1(RPNParams P) {
  int bl = blockIdx.x, b = bl / 5, l = bl % 5;
  int N = c_N[l], K = c_K[l];
  int chunk = (N + 31) / 32;
  int i0 = blockIdx.y * chunk;
  int i1 = i0 + chunk; if (i1 > N) i1 = N;
  const float4* c4 = (const float4*)(P.ctr[l] + (size_t)b * N);
  __shared__ unsigned int S[257];
  __shared__ unsigned int wh[4][256];
  int tid = threadIdx.x, wid = tid >> 6;
  // per-block v0 from g0p partials (L2-hot; hidden by occupancy)
  {
    unsigned int s = 0;
    const unsigned int* base0 = P.g0p + (size_t)bl * 32 * 256 + tid;
    #pragma unroll 8
    for (int p = 0; p < 32; ++p) s += base0[p * 256];
    S[tid] = s;
    if (tid == 0) S[256] = 0u;
  }
  __syncthreads();
  for (int d = 1; d < 256; d <<= 1) {
    unsigned int v = (tid + d < 256) ? S[tid + d] : 0u;
    __syncthreads();
    S[tid] += v;
    __syncthreads();
  }
  int lo = 0, hi = 255;
  while (lo < hi) { int mid = (lo + hi + 1) >> 1; if (S[mid] >= (unsigned int)K) lo = mid; else hi = mid - 1; }
  unsigned int v0 = (unsigned int)lo;
  if (blockIdx.y == 0 && tid == 0) {
    P.v0kk[bl * 2] = v0;
    P.v0kk[bl * 2 + 1] = (unsigned int)K - S[lo + 1];
  }
  for (int i = tid; i < 1024; i += 256) ((unsigned int*)wh)[i] = 0u;
  __syncthreads();
  int q0 = i0 >> 2, q1 = i1 >> 2;
  for (int q = q0 + tid; q < q1; q += 256) {
    float4 v = c4[q];
    unsigned int u0 = fkey(v.x), u1 = fkey(v.y), u2 = fkey(v.z), u3 = fkey(v.w);
    if ((u0 >> 24) == v0) atomicAdd(&wh[wid][(u0 >> 16) & 255u], 1u);
    if ((u1 >> 24) == v0) atomicAdd(&wh[wid][(u1 >> 16) & 255u], 1u);
    if ((u2 >> 24) == v0) atomicAdd(&wh[wid][(u2 >> 16) & 255u], 1u);
    if ((u3 >> 24) == v0) atomicAdd(&wh[wid][(u3 >> 16) & 255u], 1u);
  }
  __syncthreads();
  int bin = tid;
  P.g1p[((size_t)bl * 32 + blockIdx.y) * 256 + bin] =
      wh[0][bin] + wh[1][bin] + wh[2][bin] + wh[3][bin];
}

// -- Phase 1c (fused): threshold + block-local compact + sort + decode ----
// One block per (img,lvl). Threshold from g1p partials (same math as the
// old k_compact); candidates compacted straight into LDS (ballot + one LDS
// atomic per nonempty wave-group; ordering nondeterminism canonicalized by
// the (key desc, idx asc) sort); then bitonic sort, decode+clip, and the
// valid-partitioned keyC write for k_merge.
__global__ __launch_bounds__(1024) void k_select(RPNParams P) {
  int bl = blockIdx.x, b = bl / 5, l = bl % 5;
  int N = c_N[l], K = c_K[l];
  const float* ctr = P.ctr[l] + (size_t)b * N;
  const float4* c4 = (const float4*)ctr;
  __shared__ unsigned long long cand[kCandMax];
  __shared__ unsigned int S4[4][256];
  __shared__ unsigned int S[257];
  __shared__ unsigned int candCount;
  __shared__ unsigned int wsum[16];
  __shared__ unsigned int sTot;
  int tid = threadIdx.x;
  int lane = tid & 63, wid = tid >> 6;
  // ---- threshold from g1p partials + v0kk (identical math to r13) ----
  {
    int bin = tid & 255, qq = tid >> 8;
    unsigned int s = 0;
    const unsigned int* base1 = P.g1p + (size_t)bl * 32 * 256 + bin;
    #pragma unroll
    for (int p = 0; p < 8; ++p) s += base1[(qq * 8 + p) * 256];
    S4[qq][bin] = s;
  }
  if (tid == 0) candCount = 0u;
  __syncthreads();
  if (tid < 256) {
    S[tid] = S4[0][tid] + S4[1][tid] + S4[2][tid] + S4[3][tid];
    if (tid == 0) S[256] = 0u;
  }
  __syncthreads();
  for (int d = 1; d < 256; d <<= 1) {
    unsigned int v = 0;
    if (tid < 256 && tid + d < 256) v = S[tid + d];
    __syncthreads();
    if (tid < 256) S[tid] += v;
    __syncthreads();
  }
  unsigned int v0 = P.v0kk[bl * 2], kk = P.v0kk[bl * 2 + 1];
  int lo = 0, hi = 255;
  while (lo < hi) { int mid = (lo + hi + 1) >> 1; if (S[mid] >= kk) lo = mid; else hi = mid - 1; }
  unsigned int T = ((v0 << 8) | (unsigned int)lo) << 16;
  // ---- block-local compaction into LDS ----
  int qn = N >> 2;
  unsigned long long lmlt = (1ull << lane) - 1ull;
  for (int q = tid; q < qn; q += 1024) {
    float4 v = c4[q];
    unsigned int u[4] = {fkey(v.x), fkey(v.y), fkey(v.z), fkey(v.w)};
    #pragma unroll
    for (int k = 0; k < 4; ++k) {
      bool pred = (u[k] >= T);
      unsigned long long m = __ballot(pred);
      if (m) {
        unsigned int base = 0;
        if (lane == 0) base = atomicAdd(&candCount, (unsigned int)__popcll(m));
        base = (unsigned int)__shfl((int)base, 0, 64);
        if (pred) {
          unsigned int pos = base + (unsigned int)__popcll(m & lmlt);
          if (pos < (unsigned int)kCandMax) {
            unsigned int idx = (unsigned int)(q * 4 + k);
            cand[pos] = ((unsigned long long)u[k] << 32) |
                        (unsigned long long)(0xFFFFFFFFu - idx);
          }
        }
      }
    }
  }
  __syncthreads();
  int cc = (int)candCount; if (cc > kCandMax) cc = kCandMax;
  int n2 = 1; while (n2 < cc) n2 <<= 1;
  for (int i = cc + tid; i < n2; i += 1024) cand[i] = 0ull;
  __syncthreads();
  // bitonic sort descending by (key desc, idx asc) composite
  for (int size = 2; size <= n2; size <<= 1) {
    for (int stride = size >> 1; stride > 0; stride >>= 1) {
      for (int i = tid; i < n2; i += 1024) {
        int j = i ^ stride;
        if (j > i) {
          unsigned long long a = cand[i], c2 = cand[j];
          bool sw = ((i & size) == 0) ? (a < c2) : (a > c2);
          if (sw) { cand[i] = c2; cand[j] = a; }
        }
      }
      __syncthreads();
    }
  }
  size_t sbase = ((size_t)b * 5 + l) * 1024;
  int r = tid;  // K <= 1000 < 1024: single round
  unsigned long long kc = 0ull;
  bool flag = false;
  if (r < K) {
    unsigned long long cv = cand[r];
    unsigned int idx = 0xFFFFFFFFu - (unsigned int)(cv & 0xFFFFFFFFu);
    float s = ctr[idx];
    float4 anc = *(const float4*)(P.anchors[l] + (size_t)idx * 4);
    float4 dd  = *(const float4*)(P.deltas[l] + ((size_t)b * N + idx) * 4);
    // Box2BoxTransformLinear decode (same op order as reference, no fma)
    float w = anc.z - anc.x, hgt = anc.w - anc.y;
    float cx = (anc.x + anc.z) * 0.5f, cy = (anc.y + anc.w) * 0.5f;
    float x1 = cx - dd.x * w;
    float y1 = cy - dd.y * hgt;
    float x2 = cx + dd.z * w;
    float y2 = cy + dd.w * hgt;
    x1 = fminf(fmaxf(x1, 0.0f), 1024.0f);
    y1 = fminf(fmaxf(y1, 0.0f), 1024.0f);
    x2 = fminf(fmaxf(x2, 0.0f), 1024.0f);
    y2 = fminf(fmaxf(y2, 0.0f), 1024.0f);
    bool valid = ((x2 - x1) > 0.0f) && ((y2 - y1) > 0.0f);
    float sc = valid ? s : -INFINITY;
    P.scores[sbase + r] = sc;
    *(float4*)(P.boxes + (sbase + r) * 4) = make_float4(x1, y1, x2, y2);
    unsigned int fk = fkey(sc);
    flag = fk > 0x007FFFFFu;  // score > -inf
    unsigned int cidx = (unsigned int)(l * 1000 + r);
    kc = ((unsigned long long)fk << 32) |
         (unsigned long long)(0xFFFFFFFFu - cidx);
  }
  // stable partition (valid first) -> keyC, strictly descending composite
  unsigned int fv = flag ? 1u : 0u, v = fv;
  for (int d = 1; d < 64; d <<= 1) {
    unsigned int n = __shfl_up(v, (unsigned int)d, 64);
    if (lane >= d) v += n;
  }
  if (lane == 63) wsum[wid] = v;
  __syncthreads();
  if (tid == 0) {
    unsigned int acc = 0;
    for (int w = 0; w < 16; ++w) { unsigned int x = wsum[w]; wsum[w] = acc; acc += x; }
    sTot = acc;
  }
  __syncthreads();
  unsigned int excl = wsum[wid] + (v - fv);
  if (r < K) {
    unsigned int dest = flag ? excl : (sTot + ((unsigned int)r - excl));
    P.keyC[(size_t)bl * 1024 + dest] = kc;
  }
}

// ---------------- Phase 2a: suppression bitmask (per level) ---------------
__global__ __launch_bounds__(512) void k_mask(RPNParams P) {
  int bl = blockIdx.x, b = bl / 5, l = bl % 5;
  int K = c_K[l];
  int tid = threadIdx.x;
  int lane = tid & 63;
  int yg = blockIdx.y * 8 + (tid >> 6);   // row-group 0..15
  int zc = blockIdx.z;                    // column sixteenth 0..15
  float off = (float)l * 1025.0f;  // lvl * (IMG + 1) — replicate offset rounding!
  size_t sbase = ((size_t)b * 5 + l) * 1024;
  __shared__ alignas(16) float4 obox[1024];
  __shared__ float area[1024];
  for (int i = tid; i < 1024; i += 512) {
    float4 v = make_float4(0.f, 0.f, 0.f, 0.f);
    if (i < K) {
      v = ((const float4*)P.boxes)[sbase + i];
      v.x += off; v.y += off; v.z += off; v.w += off;
    }
    obox[i] = v;
    area[i] = fmaxf(v.z - v.x, 0.0f) * fmaxf(v.w - v.y, 0.0f);
  }
  __syncthreads();
  int i = yg * 64 + lane;
  if (i >= K) return;  // after the barrier; no further barriers below
  float4 bi = obox[i];
  float ai = area[i];
  unsigned int* mrow = P.mask + (sbase + (size_t)i) * 32;
  const double M = 0x1.666667p-1;  // 0.7f + 2^-25
  auto pr = [&](int j) -> bool {
    float4 bj = obox[j];
    float aj = area[j];
    float xx1 = fmaxf(bi.x, bj.x);
    float yy1 = fmaxf(bi.y, bj.y);
    float xx2 = fminf(bi.z, bj.z);
    float yy2 = fminf(bi.w, bj.w);
    float ww = fmaxf(xx2 - xx1, 0.0f);
    float hh = fmaxf(yy2 - yy1, 0.0f);
    float inter = ww * hh;
    float uni = ai + aj - inter + 1e-8f;  // ((ai+aj)-inter)+eps, f32 order
    return (double)inter >= M * (double)uni;
  };
  int wown = 2 * yg;
  if (zc == 0) {
    for (int w = 0; w < wown; ++w) mrow[w] = 0u;  // low words: all j < own pair
    // own word pair: transposed (j < i) bits
    unsigned int m0, m1;
    if (lane < 32) { m0 = (1u << lane) - 1u; m1 = 0u; }
    else           { m0 = 0xFFFFFFFFu; m1 = (1u << (lane - 32)) - 1u; }
    #pragma unroll
    for (int h = 0; h < 2; ++h) {
      unsigned int bits = 0u;
      int j0 = (wown + h) << 5;
      for (int jj = 0; jj < 32; ++jj)
        if (pr(j0 + jj)) bits |= (1u << jj);
      mrow[wown + h] = bits & (h ? m1 : m0);
    }
  }
  int wstart = wown + 2;
  int nw = 32 - wstart;
  int qlen = (nw + 15) >> 4;
  int wbeg = wstart + zc * qlen;
  int wend = wbeg + qlen; if (wend > 32) wend = 32;
  for (int w = wbeg; w < wend; ++w) {
    unsigned int bits = 0u;
    int j0 = w << 5;
    for (int jj = 0; jj < 32; ++jj)
      if (pr(j0 + jj)) bits |= (1u << jj);  // j > i guaranteed (w > own pair)
    mrow[w] = bits;
  }
}

// ---------------- Phase 2b: greedy sweep, parallel peel -------------------
__global__ __launch_bounds__(1024) void k_sweep(RPNParams P) {
  int bl = blockIdx.x, b = bl / 5, l = bl % 5;
  int K = c_K[l];
  int NW = (K + 63) >> 6;
  size_t sbase = ((size_t)b * 5 + l) * 1024;
  __shared__ alignas(16) unsigned long long lmask[16 * 1000];  // 125 KiB [row][16]
  __shared__ unsigned long long rdiag[1024];  // colmask per row (earlier in-word)
  __shared__ unsigned long long svalid[16];
  __shared__ unsigned long long skept[16];
  int tid = threadIdx.x;
  const ulonglong2* gm2 = (const ulonglong2*)(P.mask + sbase * 32);
  for (int j = tid; j < K * 8; j += 1024) {
    ulonglong2 v = gm2[j];
    ((ulonglong2*)lmask)[j] = v;
    int w0i = j * 2;       // u64 index within the matrix
    int row = w0i >> 4;
    int dcol = row >> 6;   // the row's own-word u64 slot
    int col0 = w0i & 15;
    if (col0 == dcol) rdiag[row] = v.x;
    else if (col0 + 1 == dcol) rdiag[row] = v.y;
  }
  // valid ballots computed by all 16 waves in parallel (wave g -> word g)
  {
    int g = tid >> 6;
    int e = g * 64 + (tid & 63);
    bool pred = (e < K) && (P.scores[sbase + e] > -INFINITY);
    unsigned long long m = __ballot(pred);
    if ((tid & 63) == 0) svalid[g] = m;
  }
  __syncthreads();
  if (tid >= 64) return;  // single wave from here; no further barriers
  int lane = tid;
  int sub = lane >> 4, col = lane & 15;
  unsigned long long accA = 0ull, accB = 0ull;  // per-lane partial OR of kept rows
  for (int g = 0; g < NW; ++g) {
    // combine the 4 subset-partials for column g (lanes g, g+16, g+32, g+48)
    unsigned long long am = accA | accB;
    unsigned long long suppr = readlane64(am, g) | readlane64(am, g + 16) |
                               readlane64(am, g + 32) | readlane64(am, g + 48);
    unsigned long long A = svalid[g] & ~suppr;   // alive set (wave-uniform value)
    unsigned long long colmask = rdiag[g * 64 + lane];  // earlier in-word suppressors
    unsigned long long kept = 0ull;
    while (A) {  // level-synchronous peel == sequential greedy
      bool cand = (A >> lane) & 1ull;
      unsigned long long D = __ballot(cand && ((colmask & A) == 0ull));
      kept |= D;
      unsigned long long sup = __ballot((colmask & D) != 0ull);
      A &= ~(D | sup);
    }
    if (lane == 0) skept[g] = kept;
    // static unrolled OR of kept rows into per-lane acc (columns for later words)
    const unsigned long long* rowbase = &lmask[((size_t)g * 64 + (size_t)sub) * 16 + col];
    #pragma unroll
    for (int t = 0; t < 8; ++t) {
      int p0 = (2 * t) * 4 + sub;
      int p1 = (2 * t + 1) * 4 + sub;
      unsigned long long s0 = 0ull - ((kept >> p0) & 1ull);
      unsigned long long s1 = 0ull - ((kept >> p1) & 1ull);
      accA |= rowbase[(size_t)(2 * t) * 64] & s0;
      accB |= rowbase[(size_t)(2 * t + 1) * 64] & s1;
    }
  }
  for (int g = 0; g < NW; ++g) {
    unsigned long long kv = skept[g];
    int e = g * 64 + lane;
    if (e < K) P.keep[sbase + e] = (unsigned char)((kv >> lane) & 1ull);
  }
}

// ------- Phase 3: per-image 5-way merge-by-rank + keep-partition + out ----
__global__ __launch_bounds__(1024) void k_merge(RPNParams P) {
  int b = blockIdx.x;
  __shared__ unsigned long long keyL[5][1000];  // 40 KB, strictly desc per level
  __shared__ unsigned short srt[4768];          // rank -> concat idx
  __shared__ unsigned int wsum[16];
  __shared__ unsigned int sTot;
  int tid = threadIdx.x;
  int lane = tid & 63, wid = tid >> 6;

  // ---- Step 1: load pre-partitioned keys (from k_select) ----
  #pragma unroll
  for (int l = 0; l < 5; ++l)
    if (tid < c_K[l]) keyL[l][tid] = P.keyC[((size_t)b * 5 + l) * 1024 + tid];
  __syncthreads();

  // ---- Step 2: global rank via binary search in the other 4 lists ----
  for (int e = tid; e < 4768; e += 1024) {
    int l = (e < 4000) ? (e / 1000) : 4;
    int p = e - l * 1000;
    unsigned long long k = keyL[l][p];
    int rank = p;
    #pragma unroll
    for (int l2 = 0; l2 < 5; ++l2) {
      if (l2 == l) continue;
      int lo = 0, hi = c_K[l2];
      while (lo < hi) {
        int mid = (lo + hi) >> 1;
        if (keyL[l2][mid] > k) lo = mid + 1; else hi = mid;
      }
      rank += lo;
    }
    srt[rank] = (unsigned short)(0xFFFFFFFFu - (unsigned int)(k & 0xFFFFFFFFu));
  }
  __syncthreads();

  // ---- Step 3: keep flags for 5 contiguous sorted slots per thread ----
  int base = tid * 5;
  unsigned char lf[5];
  unsigned short lc[5];
  unsigned int lsum = 0;
  for (int q = 0; q < 5; ++q) {
    int i = base + q;
    unsigned char f = 0; unsigned short cx = 0;
    if (i < 4768) {
      cx = srt[i];
      int l = cx / 1000;
      int r = (int)cx - l * 1000;
      f = P.keep[((size_t)b * 5 + l) * 1024 + r];
    }
    lf[q] = f; lc[q] = cx; lsum += f;
  }
  unsigned int v = lsum;
  for (int d = 1; d < 64; d <<= 1) {
    unsigned int n = __shfl_up(v, (unsigned int)d, 64);
    if (lane >= d) v += n;
  }
  if (lane == 63) wsum[wid] = v;
  __syncthreads();
  if (tid == 0) {
    unsigned int acc = 0;
    for (int w = 0; w < 16; ++w) { unsigned int x = wsum[w]; wsum[w] = acc; acc += x; }
    sTot = acc;
  }
  __syncthreads();
  unsigned int excl = wsum[wid] + (v - lsum);  // kept count before slot `base`
  unsigned int tot = sTot;
  for (int q = 0; q < 5; ++q) {
    int i = base + q;
    if (i >= 4768) break;
    unsigned int cidx = (unsigned int)lc[q];
    int l = (int)(cidx / 1000u);
    int r = (int)cidx - l * 1000;
    size_t sb = ((size_t)b * 5 + l) * 1024 + r;
    unsigned char f = lf[q];
    unsigned int pos = f ? excl : (tot + ((unsigned int)i - excl));
    excl += f;
    if (pos < 1000u) {
      float4 bx = ((const float4*)P.boxes)[sb];
      float sc = f ? P.scores[sb] : -INFINITY;
      float* o = P.out + ((size_t)b * 1000 + pos) * 5;
      o[0] = bx.x; o[1] = bx.y; o[2] = bx.z; o[3] = bx.w; o[4] = sc;
    }
  }
}

}  // namespace

extern "C" void kernel_launch(void* const* d_in, const int* in_sizes, int n_in,
                              void* d_out, int out_size, void* d_ws, size_t ws_size,
                              hipStream_t stream) {
  (void)out_size; (void)ws_size;
  RPNParams P;
  bool interleaved = (n_in >= 3) && (in_sizes[2] == 786432);
  for (int l = 0; l < 5; ++l) {
    if (interleaved) {
      P.deltas[l]  = (const float*)d_in[3 * l + 0];
      P.ctr[l]     = (const float*)d_in[3 * l + 1];
      P.anchors[l] = (const float*)d_in[3 * l + 2];
    } else {
      P.deltas[l]  = (const float*)d_in[l];
      P.ctr[l]     = (const float*)d_in[5 + l];
      P.anchors[l] = (const float*)d_in[10 + l];
    }
  }
  char* ws = (char*)d_ws;
  P.scores = (float*)(ws + 0);                    // 163840 B
  P.boxes  = (float*)(ws + 163840);               // 655360 B
  P.keep   = (unsigned char*)(ws + 819200);       // 40960 B
  P.mask   = (unsigned int*)(ws + 860160);        // 5242880 B
  // aliases inside the mask region (all used strictly before k_mask writes):
  P.g0p    = (unsigned int*)(ws + 2170880);       // 1310720 B
  P.g1p    = (unsigned int*)(ws + 3481600);       // 1310720 B
  // small control arrays (all rewritten every launch; no init needed):
  P.v0kk   = (unsigned int*)(ws + 6144000);       // 320 B
  P.keyC   = (unsigned long long*)(ws + 6144320); // 327680 B
  P.out    = (float*)d_out;

  hipLaunchKernelGGL(k_hist0, dim3(40, 32), dim3(256), 0, stream, P);
  hipLaunchKernelGGL(k_hist1, dim3(40, 32), dim3(256), 0, stream, P);
  hipLaunchKernelGGL(k_select, dim3(40), dim3(1024), 0, stream, P);
  hipLaunchKernelGGL(k_mask, dim3(40, 2, 16), dim3(512), 0, stream, P);
  hipLaunchKernelGGL(k_sweep, dim3(40), dim3(1024), 0, stream, P);
  hipLaunchKernelGGL(k_merge, dim3(8), dim3(1024), 0, stream, P);
}

// Round 16
// 116.186 us; speedup vs baseline: 3.5620x; 1.1058x over previous
//
#include <hip/hip_runtime.h>
#include <cstdint>
#include <cstddef>
#include <cmath>

#pragma clang fp contract(off)

namespace {

constexpr int kCandMax = 4096;

__device__ __constant__ int c_N[5] = {196608, 49152, 12288, 3072, 768};
__device__ __constant__ int c_K[5] = {1000, 1000, 1000, 1000, 768};

struct RPNParams {
  const float* deltas[5];
  const float* ctr[5];
  const float* anchors[5];
  float* scores;         // [8][5][1024] masked scores, per-level sorted desc
  float* boxes;          // [8][5][1024][4] clipped boxes, per-level sorted
  unsigned char* keep;   // [8][5][1024]
  unsigned int* mask;    // [8][5][1024][32]; own-pair u64 holds TRANSPOSED bits
  unsigned short* g12;   // [40][8][4096] u16 partial 12-bit hists (aliases mask region)
  unsigned int* ccount;  // [40] at stride 256 u32 (own cache line each)
  unsigned long long* cand;  // [40][4096] (aliases mask region; used before k_mask)
  unsigned long long* keyC;  // [40][1024] valid-partitioned composite keys
  float* out;            // [8][1000][5]
};

// monotonic float->uint map (larger float => larger uint)
__device__ __forceinline__ unsigned int fkey(float f) {
  unsigned int u = __float_as_uint(f);
  return (u & 0x80000000u) ? ~u : (u | 0x80000000u);
}

__device__ __forceinline__ unsigned long long readlane64(unsigned long long v, int lane) {
  unsigned int lo = __builtin_amdgcn_readlane((unsigned int)v, lane);
  unsigned int hi = __builtin_amdgcn_readlane((unsigned int)(v >> 32), lane);
  return ((unsigned long long)hi << 32) | (unsigned long long)lo;
}

// ------- Phase 1a: single-pass 12-bit partial histograms (plain stores) ---
// 4096 bins (fkey>>20 = sign+8exp+3mant). Threshold-bin width at z~2.5 is
// 0.25 -> candidates stay <= ~1350 for every level (3x margin vs kCandMax);
// u16 partials (max partial-bin count ~700). 4 LDS copies (wave-pair each).
__global__ __launch_bounds__(512) void k_hist(RPNParams P) {
  int bl = blockIdx.x, b = bl / 5, l = bl % 5;
  int N = c_N[l];
  int chunk = N / 8;  // all N divisible by 8; chunk divisible by 4
  int i0 = blockIdx.y * chunk;
  const float4* c4 = (const float4*)(P.ctr[l] + (size_t)b * N);
  __shared__ unsigned int wh[4][4096];  // 64 KiB
  int tid = threadIdx.x;
  int cp = tid >> 7;  // wave-pair copy index 0..3
  if (blockIdx.y == 0 && tid == 0) P.ccount[bl * 256] = 0u;  // pre-zero
  for (int i = tid; i < 4096; i += 512) ((uint4*)wh)[i] = make_uint4(0, 0, 0, 0);
  __syncthreads();
  unsigned int* myh = wh[cp];
  int q0 = i0 >> 2, q1 = (i0 + chunk) >> 2;
  for (int q = q0 + tid; q < q1; q += 512) {
    float4 v = c4[q];
    atomicAdd(&myh[fkey(v.x) >> 20], 1u);
    atomicAdd(&myh[fkey(v.y) >> 20], 1u);
    atomicAdd(&myh[fkey(v.z) >> 20], 1u);
    atomicAdd(&myh[fkey(v.w) >> 20], 1u);
  }
  __syncthreads();
  unsigned short* dst = P.g12 + ((size_t)bl * 8 + blockIdx.y) * 4096;
  for (int bin = tid; bin < 4096; bin += 512)
    dst[bin] = (unsigned short)(wh[0][bin] + wh[1][bin] + wh[2][bin] + wh[3][bin]);
}

// ---- Phase 1b: compaction; 12-bit threshold per block; one atomic -------
__global__ __launch_bounds__(256) void k_compact(RPNParams P) {
  int bl = blockIdx.x, b = bl / 5, l = bl % 5;
  int N = c_N[l];
  unsigned int K = (unsigned int)c_K[l];
  int chunk = N / 32;
  int i0 = blockIdx.y * chunk;
  const float4* c4 = (const float4*)(P.ctr[l] + (size_t)b * N);
  unsigned long long* cand = P.cand + (size_t)bl * kCandMax;
  __shared__ unsigned int S[257];
  __shared__ int sV;
  __shared__ unsigned int wcnt[4], wbase[4];
  int tid = threadIdx.x, lane = tid & 63, wid = tid >> 6;
  if (tid == 0) sV = 0;
  // per-thread 16-bin slice: sum 8 partials, local suffix
  unsigned int ls[16];
  {
    const unsigned short* base = P.g12 + (size_t)bl * 8 * 4096 + tid * 16;
    #pragma unroll
    for (int j = 0; j < 16; ++j) {
      unsigned int s = 0;
      #pragma unroll
      for (int p = 0; p < 8; ++p) s += base[p * 4096 + j];
      ls[j] = s;
    }
    #pragma unroll
    for (int j = 14; j >= 0; --j) ls[j] += ls[j + 1];  // local suffix
    S[tid] = ls[0];
    if (tid == 0) S[256] = 0u;
  }
  __syncthreads();
  for (int d = 1; d < 256; d <<= 1) {
    unsigned int v = (tid + d < 256) ? S[tid + d] : 0u;
    __syncthreads();
    S[tid] += v;
    __syncthreads();
  }
  {
    unsigned int excl = (tid < 255) ? S[tid + 1] : 0u;
    int v = -1;
    #pragma unroll
    for (int j = 15; j >= 0; --j)
      if (v < 0 && ls[j] + excl >= K) v = tid * 16 + j;
    if (v >= 0) atomicMax(&sV, v);
  }
  __syncthreads();
  unsigned int T = ((unsigned int)sV) << 20;
  int q0 = i0 >> 2, q1 = (i0 + chunk) >> 2;
  // pass 1: count
  unsigned int cnt = 0;
  for (int q = q0 + tid; q < q1; q += 256) {
    float4 v = c4[q];
    cnt += (fkey(v.x) >= T) + (fkey(v.y) >= T) + (fkey(v.z) >= T) + (fkey(v.w) >= T);
  }
  for (int d = 32; d > 0; d >>= 1) cnt += (unsigned int)__shfl_xor((int)cnt, d, 64);
  if (lane == 0) wcnt[wid] = cnt;
  __syncthreads();
  if (tid == 0) {
    unsigned int tot = wcnt[0] + wcnt[1] + wcnt[2] + wcnt[3];
    unsigned int base = tot ? atomicAdd(&P.ccount[bl * 256], tot) : 0u;
    unsigned int acc = base;
    for (int w = 0; w < 4; ++w) { unsigned int x = wcnt[w]; wbase[w] = acc; acc += x; }
  }
  __syncthreads();
  unsigned int off = wbase[wid];
  unsigned long long lmlt = (1ull << lane) - 1ull;
  for (int q = q0 + tid; q < q1; q += 256) {
    float4 v = c4[q];
    unsigned int u[4] = {fkey(v.x), fkey(v.y), fkey(v.z), fkey(v.w)};
    #pragma unroll
    for (int k = 0; k < 4; ++k) {
      bool pred = (u[k] >= T);
      unsigned long long m = __ballot(pred);
      if (pred) {
        unsigned int pos = off + (unsigned int)__popcll(m & lmlt);
        if (pos < (unsigned int)kCandMax) {
          unsigned int idx = (unsigned int)(q * 4 + k);
          cand[pos] = ((unsigned long long)u[k] << 32) |
                      (unsigned long long)(0xFFFFFFFFu - idx);
        }
      }
      off += (unsigned int)__popcll(m);
    }
  }
}

// -- Phase 1c: sort, decode+clip, write valid-partitioned keyC (40 blocks) --
__global__ __launch_bounds__(1024) void k_select(RPNParams P) {
  int bl = blockIdx.x, b = bl / 5, l = bl % 5;
  int N = c_N[l], K = c_K[l];
  const float* ctr = P.ctr[l] + (size_t)b * N;
  __shared__ unsigned long long cand[kCandMax];
  __shared__ unsigned int wsum[16];
  __shared__ unsigned int sTot;
  int tid = threadIdx.x;
  int lane = tid & 63, wid = tid >> 6;
  int cc = (int)P.ccount[bl * 256]; if (cc > kCandMax) cc = kCandMax;
  const unsigned long long* gc = P.cand + (size_t)bl * kCandMax;
  for (int i = tid; i < cc; i += 1024) cand[i] = gc[i];
  int n2 = 1; while (n2 < cc) n2 <<= 1;
  for (int i = cc + tid; i < n2; i += 1024) cand[i] = 0ull;
  __syncthreads();
  // bitonic sort descending by (key desc, idx asc) composite
  for (int size = 2; size <= n2; size <<= 1) {
    for (int stride = size >> 1; stride > 0; stride >>= 1) {
      for (int i = tid; i < n2; i += 1024) {
        int j = i ^ stride;
        if (j > i) {
          unsigned long long a = cand[i], c2 = cand[j];
          bool sw = ((i & size) == 0) ? (a < c2) : (a > c2);
          if (sw) { cand[i] = c2; cand[j] = a; }
        }
      }
      __syncthreads();
    }
  }
  size_t sbase = ((size_t)b * 5 + l) * 1024;
  int r = tid;  // K <= 1000 < 1024: single round
  unsigned long long kc = 0ull;
  bool flag = false;
  if (r < K) {
    unsigned long long cv = cand[r];
    unsigned int idx = 0xFFFFFFFFu - (unsigned int)(cv & 0xFFFFFFFFu);
    float s = ctr[idx];
    float4 anc = *(const float4*)(P.anchors[l] + (size_t)idx * 4);
    float4 dd  = *(const float4*)(P.deltas[l] + ((size_t)b * N + idx) * 4);
    // Box2BoxTransformLinear decode (same op order as reference, no fma)
    float w = anc.z - anc.x, hgt = anc.w - anc.y;
    float cx = (anc.x + anc.z) * 0.5f, cy = (anc.y + anc.w) * 0.5f;
    float x1 = cx - dd.x * w;
    float y1 = cy - dd.y * hgt;
    float x2 = cx + dd.z * w;
    float y2 = cy + dd.w * hgt;
    x1 = fminf(fmaxf(x1, 0.0f), 1024.0f);
    y1 = fminf(fmaxf(y1, 0.0f), 1024.0f);
    x2 = fminf(fmaxf(x2, 0.0f), 1024.0f);
    y2 = fminf(fmaxf(y2, 0.0f), 1024.0f);
    bool valid = ((x2 - x1) > 0.0f) && ((y2 - y1) > 0.0f);
    float sc = valid ? s : -INFINITY;
    P.scores[sbase + r] = sc;
    *(float4*)(P.boxes + (sbase + r) * 4) = make_float4(x1, y1, x2, y2);
    unsigned int fk = fkey(sc);
    flag = fk > 0x007FFFFFu;  // score > -inf
    unsigned int cidx = (unsigned int)(l * 1000 + r);
    kc = ((unsigned long long)fk << 32) |
         (unsigned long long)(0xFFFFFFFFu - cidx);
  }
  // stable partition (valid first) -> keyC, strictly descending composite
  unsigned int fv = flag ? 1u : 0u, v = fv;
  for (int d = 1; d < 64; d <<= 1) {
    unsigned int n = __shfl_up(v, (unsigned int)d, 64);
    if (lane >= d) v += n;
  }
  if (lane == 63) wsum[wid] = v;
  __syncthreads();
  if (tid == 0) {
    unsigned int acc = 0;
    for (int w = 0; w < 16; ++w) { unsigned int x = wsum[w]; wsum[w] = acc; acc += x; }
    sTot = acc;
  }
  __syncthreads();
  unsigned int excl = wsum[wid] + (v - fv);
  if (r < K) {
    unsigned int dest = flag ? excl : (sTot + ((unsigned int)r - excl));
    P.keyC[(size_t)bl * 1024 + dest] = kc;
  }
}

// ---------------- Phase 2a: suppression bitmask (per level) ---------------
__global__ __launch_bounds__(512) void k_mask(RPNParams P) {
  int bl = blockIdx.x, b = bl / 5, l = bl % 5;
  int K = c_K[l];
  int tid = threadIdx.x;
  int lane = tid & 63;
  int yg = blockIdx.y * 8 + (tid >> 6);   // row-group 0..15
  int zc = blockIdx.z;                    // column sixteenth 0..15
  float off = (float)l * 1025.0f;  // lvl * (IMG + 1) — replicate offset rounding!
  size_t sbase = ((size_t)b * 5 + l) * 1024;
  __shared__ alignas(16) float4 obox[1024];
  __shared__ float area[1024];
  for (int i = tid; i < 1024; i += 512) {
    float4 v = make_float4(0.f, 0.f, 0.f, 0.f);
    if (i < K) {
      v = ((const float4*)P.boxes)[sbase + i];
      v.x += off; v.y += off; v.z += off; v.w += off;
    }
    obox[i] = v;
    area[i] = fmaxf(v.z - v.x, 0.0f) * fmaxf(v.w - v.y, 0.0f);
  }
  __syncthreads();
  int i = yg * 64 + lane;
  if (i >= K) return;  // after the barrier; no further barriers below
  float4 bi = obox[i];
  float ai = area[i];
  unsigned int* mrow = P.mask + (sbase + (size_t)i) * 32;
  const double M = 0x1.666667p-1;  // 0.7f + 2^-25
  auto pr = [&](int j) -> bool {
    float4 bj = obox[j];
    float aj = area[j];
    float xx1 = fmaxf(bi.x, bj.x);
    float yy1 = fmaxf(bi.y, bj.y);
    float xx2 = fminf(bi.z, bj.z);
    float yy2 = fminf(bi.w, bj.w);
    float ww = fmaxf(xx2 - xx1, 0.0f);
    float hh = fmaxf(yy2 - yy1, 0.0f);
    float inter = ww * hh;
    float uni = ai + aj - inter + 1e-8f;  // ((ai+aj)-inter)+eps, f32 order
    return (double)inter >= M * (double)uni;
  };
  int wown = 2 * yg;
  if (zc == 0) {
    for (int w = 0; w < wown; ++w) mrow[w] = 0u;  // low words: all j < own pair
    // own word pair: transposed (j < i) bits
    unsigned int m0, m1;
    if (lane < 32) { m0 = (1u << lane) - 1u; m1 = 0u; }
    else           { m0 = 0xFFFFFFFFu; m1 = (1u << (lane - 32)) - 1u; }
    #pragma unroll
    for (int h = 0; h < 2; ++h) {
      unsigned int bits = 0u;
      int j0 = (wown + h) << 5;
      for (int jj = 0; jj < 32; ++jj)
        if (pr(j0 + jj)) bits |= (1u << jj);
      mrow[wown + h] = bits & (h ? m1 : m0);
    }
  }
  int wstart = wown + 2;
  int nw = 32 - wstart;
  int qlen = (nw + 15) >> 4;
  int wbeg = wstart + zc * qlen;
  int wend = wbeg + qlen; if (wend > 32) wend = 32;
  for (int w = wbeg; w < wend; ++w) {
    unsigned int bits = 0u;
    int j0 = w << 5;
    for (int jj = 0; jj < 32; ++jj)
      if (pr(j0 + jj)) bits |= (1u << jj);  // j > i guaranteed (w > own pair)
    mrow[w] = bits;
  }
}

// ---------------- Phase 2b: greedy sweep, parallel peel -------------------
__global__ __launch_bounds__(1024) void k_sweep(RPNParams P) {
  int bl = blockIdx.x, b = bl / 5, l = bl % 5;
  int K = c_K[l];
  int NW = (K + 63) >> 6;
  size_t sbase = ((size_t)b * 5 + l) * 1024;
  __shared__ alignas(16) unsigned long long lmask[16 * 1000];  // 125 KiB [row][16]
  __shared__ unsigned long long rdiag[1024];  // colmask per row (earlier in-word)
  __shared__ unsigned long long svalid[16];
  __shared__ unsigned long long skept[16];
  int tid = threadIdx.x;
  const ulonglong2* gm2 = (const ulonglong2*)(P.mask + sbase * 32);
  for (int j = tid; j < K * 8; j += 1024) {
    ulonglong2 v = gm2[j];
    ((ulonglong2*)lmask)[j] = v;
    int w0i = j * 2;       // u64 index within the matrix
    int row = w0i >> 4;
    int dcol = row >> 6;   // the row's own-word u64 slot
    int col0 = w0i & 15;
    if (col0 == dcol) rdiag[row] = v.x;
    else if (col0 + 1 == dcol) rdiag[row] = v.y;
  }
  // valid ballots computed by all 16 waves in parallel (wave g -> word g)
  {
    int g = tid >> 6;
    int e = g * 64 + (tid & 63);
    bool pred = (e < K) && (P.scores[sbase + e] > -INFINITY);
    unsigned long long m = __ballot(pred);
    if ((tid & 63) == 0) svalid[g] = m;
  }
  __syncthreads();
  if (tid >= 64) return;  // single wave from here; no further barriers
  int lane = tid;
  int sub = lane >> 4, col = lane & 15;
  unsigned long long accA = 0ull, accB = 0ull;  // per-lane partial OR of kept rows
  for (int g = 0; g < NW; ++g) {
    // combine the 4 subset-partials for column g (lanes g, g+16, g+32, g+48)
    unsigned long long am = accA | accB;
    unsigned long long suppr = readlane64(am, g) | readlane64(am, g + 16) |
                               readlane64(am, g + 32) | readlane64(am, g + 48);
    unsigned long long A = svalid[g] & ~suppr;   // alive set (wave-uniform value)
    unsigned long long colmask = rdiag[g * 64 + lane];  // earlier in-word suppressors
    unsigned long long kept = 0ull;
    while (A) {  // level-synchronous peel == sequential greedy
      bool cand = (A >> lane) & 1ull;
      unsigned long long D = __ballot(cand && ((colmask & A) == 0ull));
      kept |= D;
      unsigned long long sup = __ballot((colmask & D) != 0ull);
      A &= ~(D | sup);
    }
    if (lane == 0) skept[g] = kept;
    // static unrolled OR of kept rows into per-lane acc (columns for later words)
    const unsigned long long* rowbase = &lmask[((size_t)g * 64 + (size_t)sub) * 16 + col];
    #pragma unroll
    for (int t = 0; t < 8; ++t) {
      int p0 = (2 * t) * 4 + sub;
      int p1 = (2 * t + 1) * 4 + sub;
      unsigned long long s0 = 0ull - ((kept >> p0) & 1ull);
      unsigned long long s1 = 0ull - ((kept >> p1) & 1ull);
      accA |= rowbase[(size_t)(2 * t) * 64] & s0;
      accB |= rowbase[(size_t)(2 * t + 1) * 64] & s1;
    }
  }
  for (int g = 0; g < NW; ++g) {
    unsigned long long kv = skept[g];
    int e = g * 64 + lane;
    if (e < K) P.keep[sbase + e] = (unsigned char)((kv >> lane) & 1ull);
  }
}

// ------- Phase 3: per-image 5-way merge-by-rank + keep-partition + out ----
__global__ __launch_bounds__(1024) void k_merge(RPNParams P) {
  int b = blockIdx.x;
  __shared__ unsigned long long keyL[5][1000];  // 40 KB, strictly desc per level
  __shared__ unsigned short srt[4768];          // rank -> concat idx
  __shared__ unsigned int wsum[16];
  __shared__ unsigned int sTot;
  int tid = threadIdx.x;
  int lane = tid & 63, wid = tid >> 6;

  // ---- Step 1: load pre-partitioned keys (from k_select) ----
  #pragma unroll
  for (int l = 0; l < 5; ++l)
    if (tid < c_K[l]) keyL[l][tid] = P.keyC[((size_t)b * 5 + l) * 1024 + tid];
  __syncthreads();

  // ---- Step 2: global rank via binary search in the other 4 lists ----
  for (int e = tid; e < 4768; e += 1024) {
    int l = (e < 4000) ? (e / 1000) : 4;
    int p = e - l * 1000;
    unsigned long long k = keyL[l][p];
    int rank = p;
    #pragma unroll
    for (int l2 = 0; l2 < 5; ++l2) {
      if (l2 == l) continue;
      int lo = 0, hi = c_K[l2];
      while (lo < hi) {
        int mid = (lo + hi) >> 1;
        if (keyL[l2][mid] > k) lo = mid + 1; else hi = mid;
      }
      rank += lo;
    }
    srt[rank] = (unsigned short)(0xFFFFFFFFu - (unsigned int)(k & 0xFFFFFFFFu));
  }
  __syncthreads();

  // ---- Step 3: keep flags for 5 contiguous sorted slots per thread ----
  int base = tid * 5;
  unsigned char lf[5];
  unsigned short lc[5];
  unsigned int lsum = 0;
  for (int q = 0; q < 5; ++q) {
    int i = base + q;
    unsigned char f = 0; unsigned short cx = 0;
    if (i < 4768) {
      cx = srt[i];
      int l = cx / 1000;
      int r = (int)cx - l * 1000;
      f = P.keep[((size_t)b * 5 + l) * 1024 + r];
    }
    lf[q] = f; lc[q] = cx; lsum += f;
  }
  unsigned int v = lsum;
  for (int d = 1; d < 64; d <<= 1) {
    unsigned int n = __shfl_up(v, (unsigned int)d, 64);
    if (lane >= d) v += n;
  }
  if (lane == 63) wsum[wid] = v;
  __syncthreads();
  if (tid == 0) {
    unsigned int acc = 0;
    for (int w = 0; w < 16; ++w) { unsigned int x = wsum[w]; wsum[w] = acc; acc += x; }
    sTot = acc;
  }
  __syncthreads();
  unsigned int excl = wsum[wid] + (v - lsum);  // kept count before slot `base`
  unsigned int tot = sTot;
  for (int q = 0; q < 5; ++q) {
    int i = base + q;
    if (i >= 4768) break;
    unsigned int cidx = (unsigned int)lc[q];
    int l = (int)(cidx / 1000u);
    int r = (int)cidx - l * 1000;
    size_t sb = ((size_t)b * 5 + l) * 1024 + r;
    unsigned char f = lf[q];
    unsigned int pos = f ? excl : (tot + ((unsigned int)i - excl));
    excl += f;
    if (pos < 1000u) {
      float4 bx = ((const float4*)P.boxes)[sb];
      float sc = f ? P.scores[sb] : -INFINITY;
      float* o = P.out + ((size_t)b * 1000 + pos) * 5;
      o[0] = bx.x; o[1] = bx.y; o[2] = bx.z; o[3] = bx.w; o[4] = sc;
    }
  }
}

}  // namespace

extern "C" void kernel_launch(void* const* d_in, const int* in_sizes, int n_in,
                              void* d_out, int out_size, void* d_ws, size_t ws_size,
                              hipStream_t stream) {
  (void)out_size; (void)ws_size;
  RPNParams P;
  bool interleaved = (n_in >= 3) && (in_sizes[2] == 786432);
  for (int l = 0; l < 5; ++l) {
    if (interleaved) {
      P.deltas[l]  = (const float*)d_in[3 * l + 0];
      P.ctr[l]     = (const float*)d_in[3 * l + 1];
      P.anchors[l] = (const float*)d_in[3 * l + 2];
    } else {
      P.deltas[l]  = (const float*)d_in[l];
      P.ctr[l]     = (const float*)d_in[5 + l];
      P.anchors[l] = (const float*)d_in[10 + l];
    }
  }
  char* ws = (char*)d_ws;
  P.scores = (float*)(ws + 0);                    // 163840 B
  P.boxes  = (float*)(ws + 163840);               // 655360 B
  P.keep   = (unsigned char*)(ws + 819200);       // 40960 B
  P.mask   = (unsigned int*)(ws + 860160);        // 5242880 B (ends 6103040)
  // aliases inside the mask region (all used strictly before k_mask writes):
  P.cand   = (unsigned long long*)(ws + 860160);  // 1310720 B (ends 2170880)
  P.g12    = (unsigned short*)(ws + 2170880);     // [40][8][4096] u16 = 2621440 B (ends 4792320)
  // small control arrays (all rewritten every launch; no init needed):
  P.ccount = (unsigned int*)(ws + 6103040);       // 40 entries at stride 256 u32
  P.keyC   = (unsigned long long*)(ws + 6144320); // 327680 B
  P.out    = (float*)d_out;

  hipLaunchKernelGGL(k_hist, dim3(40, 8), dim3(512), 0, stream, P);
  hipLaunchKernelGGL(k_compact, dim3(40, 32), dim3(256), 0, stream, P);
  hipLaunchKernelGGL(k_select, dim3(40), dim3(1024), 0, stream, P);
  hipLaunchKernelGGL(k_mask, dim3(40, 2, 16), dim3(512), 0, stream, P);
  hipLaunchKernelGGL(k_sweep, dim3(40), dim3(1024), 0, stream, P);
  hipLaunchKernelGGL(k_merge, dim3(8), dim3(1024), 0, stream, P);
}

// Round 17
// 113.277 us; speedup vs baseline: 3.6535x; 1.0257x over previous
//
#include <hip/hip_runtime.h>
#include <cstdint>
#include <cstddef>
#include <cmath>

#pragma clang fp contract(off)

namespace {

constexpr int kCandMax = 4096;

__device__ __constant__ int c_N[5] = {196608, 49152, 12288, 3072, 768};
__device__ __constant__ int c_K[5] = {1000, 1000, 1000, 1000, 768};

struct RPNParams {
  const float* deltas[5];
  const float* ctr[5];
  const float* anchors[5];
  float* scores;         // [8][5][1024] masked scores, per-level sorted desc
  float* boxes;          // [8][5][1024][4] clipped boxes, per-level sorted
  unsigned char* keep;   // [8][5][1024]
  unsigned int* mask;    // [8][5][1024][32]; own-pair u64 holds TRANSPOSED bits
  unsigned int* g0p;     // [40][32][256] partial hist level 0 (aliases mask region)
  unsigned int* g1p;     // [40][32][256] partial hist level 1 (aliases mask region)
  unsigned int* ccount;  // [40] at stride 256 u32 (own cache line each)
  unsigned int* v0kk;    // [40][2]: (v0, kk)
  unsigned long long* cand;  // [40][4096] (aliases mask region; used before k_mask)
  unsigned long long* keyC;  // [40][1024] valid-partitioned composite keys
  float* out;            // [8][1000][5]
};

// monotonic float->uint map (larger float => larger uint)
__device__ __forceinline__ unsigned int fkey(float f) {
  unsigned int u = __float_as_uint(f);
  return (u & 0x80000000u) ? ~u : (u | 0x80000000u);
}

__device__ __forceinline__ unsigned long long readlane64(unsigned long long v, int lane) {
  unsigned int lo = __builtin_amdgcn_readlane((unsigned int)v, lane);
  unsigned int hi = __builtin_amdgcn_readlane((unsigned int)(v >> 32), lane);
  return ((unsigned long long)hi << 32) | (unsigned long long)lo;
}

// ---------------- Phase 1a: 8-bit partial histograms (plain stores) ------
// 16 sub-histograms (wave x lane&3, 257-padded) cut same-address LDS-atomic
// serialization ~4x on the hot normal-distribution exponent bins.
__global__ __launch_bounds__(256) void k_hist0(RPNParams P) {
  int bl = blockIdx.x, b = bl / 5, l = bl % 5;
  int N = c_N[l];
  int chunk = (N + 31) / 32;  // multiples of 4
  int i0 = blockIdx.y * chunk;
  int i1 = i0 + chunk; if (i1 > N) i1 = N;
  const float4* c4 = (const float4*)(P.ctr[l] + (size_t)b * N);
  __shared__ unsigned int wh16[4][4][257];
  int tid = threadIdx.x, wid = tid >> 6, sg = tid & 3;
  if (blockIdx.y == 0 && tid == 0) P.ccount[bl * 256] = 0u;  // pre-zero for k_compact
  for (int i = tid; i < 4 * 4 * 257; i += 256) ((unsigned int*)wh16)[i] = 0u;
  __syncthreads();
  unsigned int* myh = wh16[wid][sg];
  int q0 = i0 >> 2, q1 = i1 >> 2;
  for (int q = q0 + tid; q < q1; q += 256) {
    float4 v = c4[q];
    atomicAdd(&myh[fkey(v.x) >> 24], 1u);
    atomicAdd(&myh[fkey(v.y) >> 24], 1u);
    atomicAdd(&myh[fkey(v.z) >> 24], 1u);
    atomicAdd(&myh[fkey(v.w) >> 24], 1u);
  }
  __syncthreads();
  int bin = tid;
  unsigned int s = 0;
  #pragma unroll
  for (int w = 0; w < 4; ++w)
    #pragma unroll
    for (int k2 = 0; k2 < 4; ++k2) s += wh16[w][k2][bin];
  P.g0p[((size_t)bl * 32 + blockIdx.y) * 256 + bin] = s;
}

// -------- Phase 1b: 16-bit partial refine (v0 computed per block) --------
__global__ __launch_bounds__(256) void k_hist1(RPNParams P) {
  int bl = blockIdx.x, b = bl / 5, l = bl % 5;
  int N = c_N[l], K = c_K[l];
  int chunk = (N + 31) / 32;
  int i0 = blockIdx.y * chunk;
  int i1 = i0 + chunk; if (i1 > N) i1 = N;
  const float4* c4 = (const float4*)(P.ctr[l] + (size_t)b * N);
  __shared__ unsigned int S[257];
  __shared__ unsigned int wh[4][256];
  int tid = threadIdx.x, wid = tid >> 6;
  // per-block v0 from g0p partials (L2-hot; hidden by occupancy)
  {
    unsigned int s = 0;
    const unsigned int* base0 = P.g0p + (size_t)bl * 32 * 256 + tid;
    #pragma unroll 8
    for (int p = 0; p < 32; ++p) s += base0[p * 256];
    S[tid] = s;
    if (tid == 0) S[256] = 0u;
  }
  __syncthreads();
  for (int d = 1; d < 256; d <<= 1) {
    unsigned int v = (tid + d < 256) ? S[tid + d] : 0u;
    __syncthreads();
    S[tid] += v;
    __syncthreads();
  }
  int lo = 0, hi = 255;
  while (lo < hi) { int mid = (lo + hi + 1) >> 1; if (S[mid] >= (unsigned int)K) lo = mid; else hi = mid - 1; }
  unsigned int v0 = (unsigned int)lo;
  if (blockIdx.y == 0 && tid == 0) {
    P.v0kk[bl * 2] = v0;
    P.v0kk[bl * 2 + 1] = (unsigned int)K - S[lo + 1];
  }
  for (int i = tid; i < 1024; i += 256) ((unsigned int*)wh)[i] = 0u;
  __syncthreads();
  int q0 = i0 >> 2, q1 = i1 >> 2;
  for (int q = q0 + tid; q < q1; q += 256) {
    float4 v = c4[q];
    unsigned int u0 = fkey(v.x), u1 = fkey(v.y), u2 = fkey(v.z), u3 = fkey(v.w);
    if ((u0 >> 24) == v0) atomicAdd(&wh[wid][(u0 >> 16) & 255u], 1u);
    if ((u1 >> 24) == v0) atomicAdd(&wh[wid][(u1 >> 16) & 255u], 1u);
    if ((u2 >> 24) == v0) atomicAdd(&wh[wid][(u2 >> 16) & 255u], 1u);
    if ((u3 >> 24) == v0) atomicAdd(&wh[wid][(u3 >> 16) & 255u], 1u);
  }
  __syncthreads();
  int bin = tid;
  P.g1p[((size_t)bl * 32 + blockIdx.y) * 256 + bin] =
      wh[0][bin] + wh[1][bin] + wh[2][bin] + wh[3][bin];
}

// ---- Phase 1c: compaction; T computed per block; one atomic per block ----
__global__ __launch_bounds__(256) void k_compact(RPNParams P) {
  int bl = blockIdx.x, b = bl / 5, l = bl % 5;
  int N = c_N[l];
  int chunk = (N + 31) / 32;
  int i0 = blockIdx.y * chunk;
  int i1 = i0 + chunk; if (i1 > N) i1 = N;
  const float4* c4 = (const float4*)(P.ctr[l] + (size_t)b * N);
  unsigned long long* cand = P.cand + (size_t)bl * kCandMax;
  __shared__ unsigned int S[257];
  __shared__ unsigned int wcnt[4], wbase[4];
  int tid = threadIdx.x, lane = tid & 63, wid = tid >> 6;
  // redundant per-block threshold from g1p partials + v0kk
  {
    unsigned int s = 0;
    const unsigned int* base1 = P.g1p + (size_t)bl * 32 * 256 + tid;
    #pragma unroll 8
    for (int p = 0; p < 32; ++p) s += base1[p * 256];
    S[tid] = s;
    if (tid == 0) S[256] = 0u;
  }
  __syncthreads();
  for (int d = 1; d < 256; d <<= 1) {
    unsigned int v = (tid + d < 256) ? S[tid + d] : 0u;
    __syncthreads();
    S[tid] += v;
    __syncthreads();
  }
  unsigned int v0 = P.v0kk[bl * 2], kk = P.v0kk[bl * 2 + 1];
  int lo = 0, hi = 255;
  while (lo < hi) { int mid = (lo + hi + 1) >> 1; if (S[mid] >= kk) lo = mid; else hi = mid - 1; }
  unsigned int T = ((v0 << 8) | (unsigned int)lo) << 16;
  int q0 = i0 >> 2, q1 = i1 >> 2;
  // pass 1: count
  unsigned int cnt = 0;
  for (int q = q0 + tid; q < q1; q += 256) {
    float4 v = c4[q];
    cnt += (fkey(v.x) >= T) + (fkey(v.y) >= T) + (fkey(v.z) >= T) + (fkey(v.w) >= T);
  }
  for (int d = 32; d > 0; d >>= 1) cnt += (unsigned int)__shfl_xor((int)cnt, d, 64);
  if (lane == 0) wcnt[wid] = cnt;
  __syncthreads();
  if (tid == 0) {
    unsigned int tot = wcnt[0] + wcnt[1] + wcnt[2] + wcnt[3];
    unsigned int base = tot ? atomicAdd(&P.ccount[bl * 256], tot) : 0u;
    unsigned int acc = base;
    for (int w = 0; w < 4; ++w) { unsigned int x = wcnt[w]; wbase[w] = acc; acc += x; }
  }
  __syncthreads();
  unsigned int off = wbase[wid];
  unsigned long long lmlt = (1ull << lane) - 1ull;
  for (int q = q0 + tid; q < q1; q += 256) {
    float4 v = c4[q];
    unsigned int u[4] = {fkey(v.x), fkey(v.y), fkey(v.z), fkey(v.w)};
    #pragma unroll
    for (int k = 0; k < 4; ++k) {
      bool pred = (u[k] >= T);
      unsigned long long m = __ballot(pred);
      if (pred) {
        unsigned int pos = off + (unsigned int)__popcll(m & lmlt);
        if (pos < (unsigned int)kCandMax) {
          unsigned int idx = (unsigned int)(q * 4 + k);
          cand[pos] = ((unsigned long long)u[k] << 32) |
                      (unsigned long long)(0xFFFFFFFFu - idx);
        }
      }
      off += (unsigned int)__popcll(m);
    }
  }
}

// -- Phase 1d: sort, decode+clip, write valid-partitioned keyC (40 blocks) --
__global__ __launch_bounds__(1024) void k_select(RPNParams P) {
  int bl = blockIdx.x, b = bl / 5, l = bl % 5;
  int N = c_N[l], K = c_K[l];
  const float* ctr = P.ctr[l] + (size_t)b * N;
  __shared__ unsigned long long cand[kCandMax];
  __shared__ unsigned int wsum[16];
  __shared__ unsigned int sTot;
  int tid = threadIdx.x;
  int lane = tid & 63, wid = tid >> 6;
  int cc = (int)P.ccount[bl * 256]; if (cc > kCandMax) cc = kCandMax;
  const unsigned long long* gc = P.cand + (size_t)bl * kCandMax;
  for (int i = tid; i < cc; i += 1024) cand[i] = gc[i];
  int n2 = 1; while (n2 < cc) n2 <<= 1;
  for (int i = cc + tid; i < n2; i += 1024) cand[i] = 0ull;
  __syncthreads();
  // bitonic sort descending by (key desc, idx asc) composite
  for (int size = 2; size <= n2; size <<= 1) {
    for (int stride = size >> 1; stride > 0; stride >>= 1) {
      for (int i = tid; i < n2; i += 1024) {
        int j = i ^ stride;
        if (j > i) {
          unsigned long long a = cand[i], c2 = cand[j];
          bool sw = ((i & size) == 0) ? (a < c2) : (a > c2);
          if (sw) { cand[i] = c2; cand[j] = a; }
        }
      }
      __syncthreads();
    }
  }
  size_t sbase = ((size_t)b * 5 + l) * 1024;
  int r = tid;  // K <= 1000 < 1024: single round
  unsigned long long kc = 0ull;
  bool flag = false;
  if (r < K) {
    unsigned long long cv = cand[r];
    unsigned int idx = 0xFFFFFFFFu - (unsigned int)(cv & 0xFFFFFFFFu);
    float s = ctr[idx];
    float4 anc = *(const float4*)(P.anchors[l] + (size_t)idx * 4);
    float4 dd  = *(const float4*)(P.deltas[l] + ((size_t)b * N + idx) * 4);
    // Box2BoxTransformLinear decode (same op order as reference, no fma)
    float w = anc.z - anc.x, hgt = anc.w - anc.y;
    float cx = (anc.x + anc.z) * 0.5f, cy = (anc.y + anc.w) * 0.5f;
    float x1 = cx - dd.x * w;
    float y1 = cy - dd.y * hgt;
    float x2 = cx + dd.z * w;
    float y2 = cy + dd.w * hgt;
    x1 = fminf(fmaxf(x1, 0.0f), 1024.0f);
    y1 = fminf(fmaxf(y1, 0.0f), 1024.0f);
    x2 = fminf(fmaxf(x2, 0.0f), 1024.0f);
    y2 = fminf(fmaxf(y2, 0.0f), 1024.0f);
    bool valid = ((x2 - x1) > 0.0f) && ((y2 - y1) > 0.0f);
    float sc = valid ? s : -INFINITY;
    P.scores[sbase + r] = sc;
    *(float4*)(P.boxes + (sbase + r) * 4) = make_float4(x1, y1, x2, y2);
    unsigned int fk = fkey(sc);
    flag = fk > 0x007FFFFFu;  // score > -inf
    unsigned int cidx = (unsigned int)(l * 1000 + r);
    kc = ((unsigned long long)fk << 32) |
         (unsigned long long)(0xFFFFFFFFu - cidx);
  }
  // stable partition (valid first) -> keyC, strictly descending composite
  unsigned int fv = flag ? 1u : 0u, v = fv;
  for (int d = 1; d < 64; d <<= 1) {
    unsigned int n = __shfl_up(v, (unsigned int)d, 64);
    if (lane >= d) v += n;
  }
  if (lane == 63) wsum[wid] = v;
  __syncthreads();
  if (tid == 0) {
    unsigned int acc = 0;
    for (int w = 0; w < 16; ++w) { unsigned int x = wsum[w]; wsum[w] = acc; acc += x; }
    sTot = acc;
  }
  __syncthreads();
  unsigned int excl = wsum[wid] + (v - fv);
  if (r < K) {
    unsigned int dest = flag ? excl : (sTot + ((unsigned int)r - excl));
    P.keyC[(size_t)bl * 1024 + dest] = kc;
  }
}

// ---------------- Phase 2a: suppression bitmask (per level) ---------------
__global__ __launch_bounds__(512) void k_mask(RPNParams P) {
  int bl = blockIdx.x, b = bl / 5, l = bl % 5;
  int K = c_K[l];
  int tid = threadIdx.x;
  int lane = tid & 63;
  int yg = blockIdx.y * 8 + (tid >> 6);   // row-group 0..15
  int zc = blockIdx.z;                    // column sixteenth 0..15
  float off = (float)l * 1025.0f;  // lvl * (IMG + 1) — replicate offset rounding!
  size_t sbase = ((size_t)b * 5 + l) * 1024;
  __shared__ alignas(16) float4 obox[1024];
  __shared__ float area[1024];
  for (int i = tid; i < 1024; i += 512) {
    float4 v = make_float4(0.f, 0.f, 0.f, 0.f);
    if (i < K) {
      v = ((const float4*)P.boxes)[sbase + i];
      v.x += off; v.y += off; v.z += off; v.w += off;
    }
    obox[i] = v;
    area[i] = fmaxf(v.z - v.x, 0.0f) * fmaxf(v.w - v.y, 0.0f);
  }
  __syncthreads();
  int i = yg * 64 + lane;
  if (i >= K) return;  // after the barrier; no further barriers below
  float4 bi = obox[i];
  float ai = area[i];
  unsigned int* mrow = P.mask + (sbase + (size_t)i) * 32;
  const double M = 0x1.666667p-1;  // 0.7f + 2^-25
  auto pr = [&](int j) -> bool {
    float4 bj = obox[j];
    float aj = area[j];
    float xx1 = fmaxf(bi.x, bj.x);
    float yy1 = fmaxf(bi.y, bj.y);
    float xx2 = fminf(bi.z, bj.z);
    float yy2 = fminf(bi.w, bj.w);
    float ww = fmaxf(xx2 - xx1, 0.0f);
    float hh = fmaxf(yy2 - yy1, 0.0f);
    float inter = ww * hh;
    float uni = ai + aj - inter + 1e-8f;  // ((ai+aj)-inter)+eps, f32 order
    return (double)inter >= M * (double)uni;
  };
  int wown = 2 * yg;
  if (zc == 0) {
    for (int w = 0; w < wown; ++w) mrow[w] = 0u;  // low words: all j < own pair
    // own word pair: transposed (j < i) bits
    unsigned int m0, m1;
    if (lane < 32) { m0 = (1u << lane) - 1u; m1 = 0u; }
    else           { m0 = 0xFFFFFFFFu; m1 = (1u << (lane - 32)) - 1u; }
    #pragma unroll
    for (int h = 0; h < 2; ++h) {
      unsigned int bits = 0u;
      int j0 = (wown + h) << 5;
      for (int jj = 0; jj < 32; ++jj)
        if (pr(j0 + jj)) bits |= (1u << jj);
      mrow[wown + h] = bits & (h ? m1 : m0);
    }
  }
  int wstart = wown + 2;
  int nw = 32 - wstart;
  int qlen = (nw + 15) >> 4;
  int wbeg = wstart + zc * qlen;
  int wend = wbeg + qlen; if (wend > 32) wend = 32;
  for (int w = wbeg; w < wend; ++w) {
    unsigned int bits = 0u;
    int j0 = w << 5;
    for (int jj = 0; jj < 32; ++jj)
      if (pr(j0 + jj)) bits |= (1u << jj);  // j > i guaranteed (w > own pair)
    mrow[w] = bits;
  }
}

// ---------------- Phase 2b: greedy sweep, parallel peel -------------------
__global__ __launch_bounds__(1024) void k_sweep(RPNParams P) {
  int bl = blockIdx.x, b = bl / 5, l = bl % 5;
  int K = c_K[l];
  int NW = (K + 63) >> 6;
  size_t sbase = ((size_t)b * 5 + l) * 1024;
  __shared__ alignas(16) unsigned long long lmask[16 * 1000];  // 125 KiB [row][16]
  __shared__ unsigned long long rdiag[1024];  // colmask per row (earlier in-word)
  __shared__ unsigned long long svalid[16];
  __shared__ unsigned long long skept[16];
  int tid = threadIdx.x;
  const ulonglong2* gm2 = (const ulonglong2*)(P.mask + sbase * 32);
  for (int j = tid; j < K * 8; j += 1024) {
    ulonglong2 v = gm2[j];
    ((ulonglong2*)lmask)[j] = v;
    int w0i = j * 2;       // u64 index within the matrix
    int row = w0i >> 4;
    int dcol = row >> 6;   // the row's own-word u64 slot
    int col0 = w0i & 15;
    if (col0 == dcol) rdiag[row] = v.x;
    else if (col0 + 1 == dcol) rdiag[row] = v.y;
  }
  // valid ballots computed by all 16 waves in parallel (wave g -> word g)
  {
    int g = tid >> 6;
    int e = g * 64 + (tid & 63);
    bool pred = (e < K) && (P.scores[sbase + e] > -INFINITY);
    unsigned long long m = __ballot(pred);
    if ((tid & 63) == 0) svalid[g] = m;
  }
  __syncthreads();
  if (tid >= 64) return;  // single wave from here; no further barriers
  int lane = tid;
  int sub = lane >> 4, col = lane & 15;
  unsigned long long accA = 0ull, accB = 0ull;  // per-lane partial OR of kept rows
  for (int g = 0; g < NW; ++g) {
    // combine the 4 subset-partials for column g (lanes g, g+16, g+32, g+48)
    unsigned long long am = accA | accB;
    unsigned long long suppr = readlane64(am, g) | readlane64(am, g + 16) |
                               readlane64(am, g + 32) | readlane64(am, g + 48);
    unsigned long long A = svalid[g] & ~suppr;   // alive set (wave-uniform value)
    unsigned long long colmask = rdiag[g * 64 + lane];  // earlier in-word suppressors
    unsigned long long kept = 0ull;
    while (A) {  // level-synchronous peel == sequential greedy
      bool cand = (A >> lane) & 1ull;
      unsigned long long D = __ballot(cand && ((colmask & A) == 0ull));
      kept |= D;
      unsigned long long sup = __ballot((colmask & D) != 0ull);
      A &= ~(D | sup);
    }
    if (lane == 0) skept[g] = kept;
    // static unrolled OR of kept rows into per-lane acc (columns for later words)
    const unsigned long long* rowbase = &lmask[((size_t)g * 64 + (size_t)sub) * 16 + col];
    #pragma unroll
    for (int t = 0; t < 8; ++t) {
      int p0 = (2 * t) * 4 + sub;
      int p1 = (2 * t + 1) * 4 + sub;
      unsigned long long s0 = 0ull - ((kept >> p0) & 1ull);
      unsigned long long s1 = 0ull - ((kept >> p1) & 1ull);
      accA |= rowbase[(size_t)(2 * t) * 64] & s0;
      accB |= rowbase[(size_t)(2 * t + 1) * 64] & s1;
    }
  }
  for (int g = 0; g < NW; ++g) {
    unsigned long long kv = skept[g];
    int e = g * 64 + lane;
    if (e < K) P.keep[sbase + e] = (unsigned char)((kv >> lane) & 1ull);
  }
}

// ------- Phase 3: per-image 5-way merge-by-rank + keep-partition + out ----
__global__ __launch_bounds__(1024) void k_merge(RPNParams P) {
  int b = blockIdx.x;
  __shared__ unsigned long long keyL[5][1000];  // 40 KB, strictly desc per level
  __shared__ unsigned short srt[4768];          // rank -> concat idx
  __shared__ unsigned int wsum[16];
  __shared__ unsigned int sTot;
  int tid = threadIdx.x;
  int lane = tid & 63, wid = tid >> 6;

  // ---- Step 1: load pre-partitioned keys (from k_select) ----
  #pragma unroll
  for (int l = 0; l < 5; ++l)
    if (tid < c_K[l]) keyL[l][tid] = P.keyC[((size_t)b * 5 + l) * 1024 + tid];
  __syncthreads();

  // ---- Step 2: global rank via binary search in the other 4 lists ----
  for (int e = tid; e < 4768; e += 1024) {
    int l = (e < 4000) ? (e / 1000) : 4;
    int p = e - l * 1000;
    unsigned long long k = keyL[l][p];
    int rank = p;
    #pragma unroll
    for (int l2 = 0; l2 < 5; ++l2) {
      if (l2 == l) continue;
      int lo = 0, hi = c_K[l2];
      while (lo < hi) {
        int mid = (lo + hi) >> 1;
        if (keyL[l2][mid] > k) lo = mid + 1; else hi = mid;
      }
      rank += lo;
    }
    srt[rank] = (unsigned short)(0xFFFFFFFFu - (unsigned int)(k & 0xFFFFFFFFu));
  }
  __syncthreads();

  // ---- Step 3: keep flags for 5 contiguous sorted slots per thread ----
  int base = tid * 5;
  unsigned char lf[5];
  unsigned short lc[5];
  unsigned int lsum = 0;
  for (int q = 0; q < 5; ++q) {
    int i = base + q;
    unsigned char f = 0; unsigned short cx = 0;
    if (i < 4768) {
      cx = srt[i];
      int l = cx / 1000;
      int r = (int)cx - l * 1000;
      f = P.keep[((size_t)b * 5 + l) * 1024 + r];
    }
    lf[q] = f; lc[q] = cx; lsum += f;
  }
  unsigned int v = lsum;
  for (int d = 1; d < 64; d <<= 1) {
    unsigned int n = __shfl_up(v, (unsigned int)d, 64);
    if (lane >= d) v += n;
  }
  if (lane == 63) wsum[wid] = v;
  __syncthreads();
  if (tid == 0) {
    unsigned int acc = 0;
    for (int w = 0; w < 16; ++w) { unsigned int x = wsum[w]; wsum[w] = acc; acc += x; }
    sTot = acc;
  }
  __syncthreads();
  unsigned int excl = wsum[wid] + (v - lsum);  // kept count before slot `base`
  unsigned int tot = sTot;
  for (int q = 0; q < 5; ++q) {
    int i = base + q;
    if (i >= 4768) break;
    unsigned int cidx = (unsigned int)lc[q];
    int l = (int)(cidx / 1000u);
    int r = (int)cidx - l * 1000;
    size_t sb = ((size_t)b * 5 + l) * 1024 + r;
    unsigned char f = lf[q];
    unsigned int pos = f ? excl : (tot + ((unsigned int)i - excl));
    excl += f;
    if (pos < 1000u) {
      float4 bx = ((const float4*)P.boxes)[sb];
      float sc = f ? P.scores[sb] : -INFINITY;
      float* o = P.out + ((size_t)b * 1000 + pos) * 5;
      o[0] = bx.x; o[1] = bx.y; o[2] = bx.z; o[3] = bx.w; o[4] = sc;
    }
  }
}

}  // namespace

extern "C" void kernel_launch(void* const* d_in, const int* in_sizes, int n_in,
                              void* d_out, int out_size, void* d_ws, size_t ws_size,
                              hipStream_t stream) {
  (void)out_size; (void)ws_size;
  RPNParams P;
  bool interleaved = (n_in >= 3) && (in_sizes[2] == 786432);
  for (int l = 0; l < 5; ++l) {
    if (interleaved) {
      P.deltas[l]  = (const float*)d_in[3 * l + 0];
      P.ctr[l]     = (const float*)d_in[3 * l + 1];
      P.anchors[l] = (const float*)d_in[3 * l + 2];
    } else {
      P.deltas[l]  = (const float*)d_in[l];
      P.ctr[l]     = (const float*)d_in[5 + l];
      P.anchors[l] = (const float*)d_in[10 + l];
    }
  }
  char* ws = (char*)d_ws;
  P.scores = (float*)(ws + 0);                    // 163840 B
  P.boxes  = (float*)(ws + 163840);               // 655360 B
  P.keep   = (unsigned char*)(ws + 819200);       // 40960 B
  P.mask   = (unsigned int*)(ws + 860160);        // 5242880 B
  // aliases inside the mask region (all used strictly before k_mask writes):
  P.cand   = (unsigned long long*)(ws + 860160);  // 1310720 B
  P.g0p    = (unsigned int*)(ws + 2170880);       // 1310720 B
  P.g1p    = (unsigned int*)(ws + 3481600);       // 1310720 B
  // small control arrays (all rewritten every launch; no init needed):
  P.ccount = (unsigned int*)(ws + 6103040);       // 40 entries at stride 256 u32
  P.v0kk   = (unsigned int*)(ws + 6144000);       // 320 B
  P.keyC   = (unsigned long long*)(ws + 6144320); // 327680 B
  P.out    = (float*)d_out;

  hipLaunchKernelGGL(k_hist0, dim3(40, 32), dim3(256), 0, stream, P);
  hipLaunchKernelGGL(k_hist1, dim3(40, 32), dim3(256), 0, stream, P);
  hipLaunchKernelGGL(k_compact, dim3(40, 32), dim3(256), 0, stream, P);
  hipLaunchKernelGGL(k_select, dim3(40), dim3(1024), 0, stream, P);
  hipLaunchKernelGGL(k_mask, dim3(40, 2, 16), dim3(512), 0, stream, P);
  hipLaunchKernelGGL(k_sweep, dim3(40), dim3(1024), 0, stream, P);
  hipLaunchKernelGGL(k_merge, dim3(8), dim3(1024), 0, stream, P);
}